// Round 1
// baseline (616.905 us; speedup 1.0000x reference)
//
#include <hip/hip_runtime.h>
#include <hip/hip_bf16.h>

#define EMBED 128
#define HEADS 16
#define NEG 0.2f

static __device__ __forceinline__ float leaky(float x) { return x > 0.f ? x : NEG * x; }

// ---------------- CSR build ----------------

__global__ void k_hist(const int* __restrict__ ei, int E, int N, int* __restrict__ deg) {
  int i = blockIdx.x * blockDim.x + threadIdx.x;
  int Et = E + N;
  if (i >= Et) return;
  int d = (i < E) ? ei[E + i] : (i - E);
  atomicAdd(&deg[d], 1);
}

__global__ __launch_bounds__(1024) void k_scan(const int* __restrict__ deg,
                                               int* __restrict__ row_ptr,
                                               int* __restrict__ cursor, int n) {
  __shared__ int s[1024];
  int offset = 0;
  for (int base = 0; base < n; base += 1024) {
    int i = base + (int)threadIdx.x;
    int v = (i < n) ? deg[i] : 0;
    s[threadIdx.x] = v;
    __syncthreads();
    for (int d = 1; d < 1024; d <<= 1) {
      int add = ((int)threadIdx.x >= d) ? s[threadIdx.x - d] : 0;
      __syncthreads();
      s[threadIdx.x] += add;
      __syncthreads();
    }
    int incl = s[threadIdx.x];
    if (i < n) { row_ptr[i] = offset + incl - v; cursor[i] = offset + incl - v; }
    int total = s[1023];
    __syncthreads();
    offset += total;
  }
  if (threadIdx.x == 0) row_ptr[n] = offset;
}

__global__ void k_scatter(const int* __restrict__ ei, int E, int N,
                          int* __restrict__ cursor, int* __restrict__ csr_src) {
  int i = blockIdx.x * blockDim.x + threadIdx.x;
  int Et = E + N;
  if (i >= Et) return;
  int s = (i < E) ? ei[i] : (i - E);
  int d = (i < E) ? ei[E + i] : (i - E);
  int pos = atomicAdd(&cursor[d], 1);
  csr_src[pos] = s;
}

// ---------------- GEMM1: h1[N,2048] = x[N,128] @ W1[128,2048] ----------------
// BM=64, BN=64, K=128 (whole), 256 threads, 4x4 microtile.

__global__ __launch_bounds__(256) void k_gemm1(const float* __restrict__ x,
                                               const float* __restrict__ W,
                                               float* __restrict__ h, int N) {
  __shared__ float As[64][132];
  __shared__ float Bs[128][68];
  int row0 = blockIdx.y * 64;
  int col0 = blockIdx.x * 64;
  int tid = threadIdx.x;
#pragma unroll
  for (int i = 0; i < 8; ++i) {            // A: 64x128 = 2048 float4
    int f4i = tid + 256 * i;
    int r = f4i >> 5, c4 = f4i & 31;
    int gr = row0 + r;
    float4 v = make_float4(0.f, 0.f, 0.f, 0.f);
    if (gr < N) v = ((const float4*)x)[(size_t)gr * 32 + c4];
    *(float4*)&As[r][c4 * 4] = v;
  }
#pragma unroll
  for (int i = 0; i < 8; ++i) {            // B: 128x64 = 2048 float4
    int f4i = tid + 256 * i;
    int r = f4i >> 4, c4 = f4i & 15;
    float4 v = *(const float4*)&W[(size_t)r * 2048 + col0 + c4 * 4];
    *(float4*)&Bs[r][c4 * 4] = v;
  }
  __syncthreads();
  int tx = tid & 15, ty = tid >> 4;
  float acc[4][4] = {};
#pragma unroll 4
  for (int k = 0; k < 128; ++k) {
    float a0 = As[ty * 4 + 0][k];
    float a1 = As[ty * 4 + 1][k];
    float a2 = As[ty * 4 + 2][k];
    float a3 = As[ty * 4 + 3][k];
    float4 b = *(const float4*)&Bs[k][tx * 4];
    acc[0][0] += a0 * b.x; acc[0][1] += a0 * b.y; acc[0][2] += a0 * b.z; acc[0][3] += a0 * b.w;
    acc[1][0] += a1 * b.x; acc[1][1] += a1 * b.y; acc[1][2] += a1 * b.z; acc[1][3] += a1 * b.w;
    acc[2][0] += a2 * b.x; acc[2][1] += a2 * b.y; acc[2][2] += a2 * b.z; acc[2][3] += a2 * b.w;
    acc[3][0] += a3 * b.x; acc[3][1] += a3 * b.y; acc[3][2] += a3 * b.z; acc[3][3] += a3 * b.w;
  }
#pragma unroll
  for (int i = 0; i < 4; ++i) {
    int gr = row0 + ty * 4 + i;
    if (gr < N) {
      *(float4*)&h[(size_t)gr * 2048 + col0 + tx * 4] =
          make_float4(acc[i][0], acc[i][1], acc[i][2], acc[i][3]);
    }
  }
}

// ---------------- attention logits layer 1: als/ald [N,16] ----------------
// one wave per (n, head)

__global__ __launch_bounds__(256) void k_al1(const float* __restrict__ h1,
                                             const float* __restrict__ a_src,
                                             const float* __restrict__ a_dst,
                                             float* __restrict__ als, float* __restrict__ ald,
                                             int N) {
  int wid = (blockIdx.x * 256 + threadIdx.x) >> 6;
  int lane = threadIdx.x & 63;
  if (wid >= N * 16) return;
  int n = wid >> 4, hh = wid & 15;
  const float2 v = *(const float2*)(h1 + (size_t)n * 2048 + hh * 128 + lane * 2);
  const float2 as = *(const float2*)(a_src + hh * 128 + lane * 2);
  const float2 ad = *(const float2*)(a_dst + hh * 128 + lane * 2);
  float ps = v.x * as.x + v.y * as.y;
  float pd = v.x * ad.x + v.y * ad.y;
  for (int off = 32; off; off >>= 1) {
    ps += __shfl_down(ps, off);
    pd += __shfl_down(pd, off);
  }
  if (lane == 0) { als[wid] = ps; ald[wid] = pd; }
}

// ---------------- layer-1 attention softmax + aggregation + bias + ELU ----------------
// one block (256 thr) per dst node; thread owns 8 channels of the 2048.

__global__ __launch_bounds__(256) void k_attn1(const float* __restrict__ h1,
                                               const float* __restrict__ als,
                                               const float* __restrict__ ald,
                                               const int* __restrict__ row_ptr,
                                               const int* __restrict__ csr,
                                               const float* __restrict__ b1,
                                               float* __restrict__ out, int N) {
  int d = blockIdx.x;
  int tid = threadIdx.x;
  int e0 = row_ptr[d];
  int deg = row_ptr[d + 1] - e0;

  __shared__ float red_m[16][17], red_s[16][17];
  __shared__ float m_h[16], iz_h[16];

  int hh = tid & 15, jj = tid >> 4;
  float aldh = ald[(size_t)d * 16 + hh];
  float mt = -1e30f, st = 0.f;
  for (int e = jj; e < deg; e += 16) {
    int s = csr[e0 + e];
    float l = leaky(als[(size_t)s * 16 + hh] + aldh);
    if (l > mt) { st = st * __expf(mt - l) + 1.f; mt = l; }
    else st += __expf(l - mt);
  }
  red_m[jj][hh] = mt;
  red_s[jj][hh] = st;
  __syncthreads();
  if (tid < 16) {
    float m = -1e30f;
#pragma unroll
    for (int k = 0; k < 16; ++k) m = fmaxf(m, red_m[k][tid]);
    float z = 0.f;
#pragma unroll
    for (int k = 0; k < 16; ++k) z += red_s[k][tid] * __expf(red_m[k][tid] - m);
    m_h[tid] = m;
    iz_h[tid] = 1.f / (z + 1e-16f);
  }
  __syncthreads();

  int hc = tid >> 4;  // head owning channels [tid*8, tid*8+8)
  float acc[8] = {0.f, 0.f, 0.f, 0.f, 0.f, 0.f, 0.f, 0.f};
  __shared__ int srcb[16];
  __shared__ float alb[16][17];
  for (int base = 0; base < deg; base += 16) {
    int nb = min(16, deg - base);
    __syncthreads();
    if (tid < nb) srcb[tid] = csr[e0 + base + tid];
    __syncthreads();
    if (tid < nb * 16) {
      int e = tid >> 4, h = tid & 15;
      int s = srcb[e];
      float l = leaky(als[(size_t)s * 16 + h] + ald[(size_t)d * 16 + h]);
      alb[e][h] = __expf(l - m_h[h]) * iz_h[h];
    }
    __syncthreads();
    for (int e = 0; e < nb; ++e) {
      float a = alb[e][hc];
      const float4* hp = (const float4*)(h1 + (size_t)srcb[e] * 2048) + tid * 2;
      float4 v0 = hp[0], v1 = hp[1];
      acc[0] += a * v0.x; acc[1] += a * v0.y; acc[2] += a * v0.z; acc[3] += a * v0.w;
      acc[4] += a * v1.x; acc[5] += a * v1.y; acc[6] += a * v1.z; acc[7] += a * v1.w;
    }
  }
  int c = tid * 8;
  float* op = out + (size_t)d * 2048 + c;
#pragma unroll
  for (int i = 0; i < 8; ++i) {
    float o = acc[i] + b1[c + i];
    op[i] = o > 0.f ? o : expm1f(o);
  }
}

// ---------------- GEMM2: g[N,128] = h1act[N,2048] @ W2[2048,128] ----------------
// BM=64, BN=128(all), BK=32, 256 threads, 4x8 microtile.

__global__ __launch_bounds__(256) void k_gemm2(const float* __restrict__ A,
                                               const float* __restrict__ W,
                                               float* __restrict__ g, int N) {
  __shared__ float As[64][36];
  __shared__ float Bs[32][132];
  int row0 = blockIdx.x * 64;
  int tid = threadIdx.x;
  int tx = tid & 15, ty = tid >> 4;
  float acc[4][8] = {};
  for (int k0 = 0; k0 < 2048; k0 += 32) {
    __syncthreads();
#pragma unroll
    for (int i = 0; i < 2; ++i) {  // A tile 64x32 = 512 float4
      int f4i = tid + 256 * i;
      int r = f4i >> 3, c4 = f4i & 7;
      int gr = row0 + r;
      float4 v = make_float4(0.f, 0.f, 0.f, 0.f);
      if (gr < N) v = *(const float4*)&A[(size_t)gr * 2048 + k0 + c4 * 4];
      *(float4*)&As[r][c4 * 4] = v;
    }
#pragma unroll
    for (int i = 0; i < 4; ++i) {  // B tile 32x128 = 1024 float4
      int f4i = tid + 256 * i;
      int r = f4i >> 5, c4 = f4i & 31;
      float4 v = *(const float4*)&W[(size_t)(k0 + r) * 128 + c4 * 4];
      *(float4*)&Bs[r][c4 * 4] = v;
    }
    __syncthreads();
#pragma unroll
    for (int kk = 0; kk < 32; ++kk) {
      float a0 = As[ty * 4 + 0][kk];
      float a1 = As[ty * 4 + 1][kk];
      float a2 = As[ty * 4 + 2][kk];
      float a3 = As[ty * 4 + 3][kk];
      float4 b0 = *(const float4*)&Bs[kk][tx * 8];
      float4 b1v = *(const float4*)&Bs[kk][tx * 8 + 4];
      acc[0][0] += a0 * b0.x; acc[0][1] += a0 * b0.y; acc[0][2] += a0 * b0.z; acc[0][3] += a0 * b0.w;
      acc[0][4] += a0 * b1v.x; acc[0][5] += a0 * b1v.y; acc[0][6] += a0 * b1v.z; acc[0][7] += a0 * b1v.w;
      acc[1][0] += a1 * b0.x; acc[1][1] += a1 * b0.y; acc[1][2] += a1 * b0.z; acc[1][3] += a1 * b0.w;
      acc[1][4] += a1 * b1v.x; acc[1][5] += a1 * b1v.y; acc[1][6] += a1 * b1v.z; acc[1][7] += a1 * b1v.w;
      acc[2][0] += a2 * b0.x; acc[2][1] += a2 * b0.y; acc[2][2] += a2 * b0.z; acc[2][3] += a2 * b0.w;
      acc[2][4] += a2 * b1v.x; acc[2][5] += a2 * b1v.y; acc[2][6] += a2 * b1v.z; acc[2][7] += a2 * b1v.w;
      acc[3][0] += a3 * b0.x; acc[3][1] += a3 * b0.y; acc[3][2] += a3 * b0.z; acc[3][3] += a3 * b0.w;
      acc[3][4] += a3 * b1v.x; acc[3][5] += a3 * b1v.y; acc[3][6] += a3 * b1v.z; acc[3][7] += a3 * b1v.w;
    }
  }
#pragma unroll
  for (int i = 0; i < 4; ++i) {
    int gr = row0 + ty * 4 + i;
    if (gr < N) {
      *(float4*)&g[(size_t)gr * 128 + tx * 8] =
          make_float4(acc[i][0], acc[i][1], acc[i][2], acc[i][3]);
      *(float4*)&g[(size_t)gr * 128 + tx * 8 + 4] =
          make_float4(acc[i][4], acc[i][5], acc[i][6], acc[i][7]);
    }
  }
}

// ---------------- attention logits layer 2 (1 head): one wave per node ----------------

__global__ __launch_bounds__(256) void k_al2(const float* __restrict__ g,
                                             const float* __restrict__ a_src,
                                             const float* __restrict__ a_dst,
                                             float* __restrict__ als, float* __restrict__ ald,
                                             int N) {
  int wid = (blockIdx.x * 256 + threadIdx.x) >> 6;
  int lane = threadIdx.x & 63;
  if (wid >= N) return;
  const float2 v = *(const float2*)(g + (size_t)wid * 128 + lane * 2);
  const float2 as = *(const float2*)(a_src + lane * 2);
  const float2 ad = *(const float2*)(a_dst + lane * 2);
  float ps = v.x * as.x + v.y * as.y;
  float pd = v.x * ad.x + v.y * ad.y;
  for (int off = 32; off; off >>= 1) {
    ps += __shfl_down(ps, off);
    pd += __shfl_down(pd, off);
  }
  if (lane == 0) { als[wid] = ps; ald[wid] = pd; }
}

// ---------------- layer-2 attention + aggregation + bias + classifier ----------------
// one block (128 thr) per dst node; thread owns 1 of the 128 channels.

__global__ __launch_bounds__(128) void k_attn2(const float* __restrict__ g,
                                               const float* __restrict__ als,
                                               const float* __restrict__ ald,
                                               const int* __restrict__ row_ptr,
                                               const int* __restrict__ csr,
                                               const float* __restrict__ b2,
                                               const float* __restrict__ Wc,
                                               const float* __restrict__ bc,
                                               float* __restrict__ out, int N) {
  int d = blockIdx.x;
  int tid = threadIdx.x;
  int e0 = row_ptr[d];
  int deg = row_ptr[d + 1] - e0;

  __shared__ float rm[128], rs[128];
  float aldd = ald[d];
  float mt = -1e30f, st = 0.f;
  for (int e = tid; e < deg; e += 128) {
    int s = csr[e0 + e];
    float l = leaky(als[s] + aldd);
    if (l > mt) { st = st * __expf(mt - l) + 1.f; mt = l; }
    else st += __expf(l - mt);
  }
  rm[tid] = mt; rs[tid] = st;
  __syncthreads();
  for (int off = 64; off; off >>= 1) {
    if (tid < off) {
      float m1 = rm[tid], s1 = rs[tid];
      float m2 = rm[tid + off], s2 = rs[tid + off];
      float m = fmaxf(m1, m2);
      rm[tid] = m;
      rs[tid] = s1 * __expf(m1 - m) + s2 * __expf(m2 - m);
    }
    __syncthreads();
  }
  float mh = rm[0];
  float invz = 1.f / (rs[0] + 1e-16f);
  __syncthreads();

  __shared__ int srcb[32];
  __shared__ float alb[32];
  float acc = 0.f;
  for (int base = 0; base < deg; base += 32) {
    int nb = min(32, deg - base);
    __syncthreads();
    if (tid < nb) {
      int s = csr[e0 + base + tid];
      srcb[tid] = s;
      float l = leaky(als[s] + aldd);
      alb[tid] = __expf(l - mh) * invz;
    }
    __syncthreads();
    for (int e = 0; e < nb; ++e) {
      acc += alb[e] * g[(size_t)srcb[e] * 128 + tid];
    }
  }
  float o = acc + b2[tid];
  float part = o * Wc[tid];
  __syncthreads();
  rs[tid] = part;
  __syncthreads();
  for (int off = 64; off; off >>= 1) {
    if (tid < off) rs[tid] += rs[tid + off];
    __syncthreads();
  }
  if (tid == 0) out[d] = rs[0] + bc[0];
}

// ---------------- launch ----------------

extern "C" void kernel_launch(void* const* d_in, const int* in_sizes, int n_in,
                              void* d_out, int out_size, void* d_ws, size_t ws_size,
                              hipStream_t stream) {
  const float* x      = (const float*)d_in[0];
  const int*   ei     = (const int*)d_in[1];
  const float* W1     = (const float*)d_in[2];
  const float* a_src1 = (const float*)d_in[3];
  const float* a_dst1 = (const float*)d_in[4];
  const float* b1     = (const float*)d_in[5];
  const float* W2     = (const float*)d_in[6];
  const float* a_src2 = (const float*)d_in[7];
  const float* a_dst2 = (const float*)d_in[8];
  const float* b2     = (const float*)d_in[9];
  const float* Wc     = (const float*)d_in[10];
  const float* bc     = (const float*)d_in[11];

  int N = in_sizes[0] / EMBED;
  int E = in_sizes[1] / 2;
  int Et = E + N;

  char* ws = (char*)d_ws;
  size_t off = 0;
  auto alloc = [&](size_t bytes) -> void* {
    void* p = ws + off;
    off += (bytes + 255) & ~(size_t)255;
    return p;
  };
  float* h1    = (float*)alloc((size_t)N * 2048 * 4);
  float* h1act = (float*)alloc((size_t)N * 2048 * 4);
  float* als1  = (float*)alloc((size_t)N * 16 * 4);
  float* ald1  = (float*)alloc((size_t)N * 16 * 4);
  float* g     = (float*)alloc((size_t)N * 128 * 4);
  float* als2  = (float*)alloc((size_t)N * 4);
  float* ald2  = (float*)alloc((size_t)N * 4);
  int* deg     = (int*)alloc((size_t)N * 4);
  int* row_ptr = (int*)alloc((size_t)(N + 1) * 4);
  int* cursor  = (int*)alloc((size_t)N * 4);
  int* csr     = (int*)alloc((size_t)Et * 4);

  hipMemsetAsync(deg, 0, (size_t)N * 4, stream);
  k_hist<<<(Et + 255) / 256, 256, 0, stream>>>(ei, E, N, deg);
  k_scan<<<1, 1024, 0, stream>>>(deg, row_ptr, cursor, N);
  k_scatter<<<(Et + 255) / 256, 256, 0, stream>>>(ei, E, N, cursor, csr);

  k_gemm1<<<dim3(2048 / 64, (N + 63) / 64), 256, 0, stream>>>(x, W1, h1, N);
  k_al1<<<(N * 16 + 3) / 4, 256, 0, stream>>>(h1, a_src1, a_dst1, als1, ald1, N);
  k_attn1<<<N, 256, 0, stream>>>(h1, als1, ald1, row_ptr, csr, b1, h1act, N);

  k_gemm2<<<(N + 63) / 64, 256, 0, stream>>>(h1act, W2, g, N);
  k_al2<<<(N + 3) / 4, 256, 0, stream>>>(g, a_src2, a_dst2, als2, ald2, N);
  k_attn2<<<N, 128, 0, stream>>>(g, als2, ald2, row_ptr, csr, b2, Wc, bc, (float*)d_out, N);
}

// Round 2
// 483.790 us; speedup vs baseline: 1.2751x; 1.2751x over previous
//
#include <hip/hip_runtime.h>
#include <hip/hip_bf16.h>

#define EMBED 128
#define HEADS 16
#define NEG 0.2f

static __device__ __forceinline__ float leaky(float x) { return x > 0.f ? x : NEG * x; }

// ---------------- CSR build ----------------

__global__ void k_hist(const int* __restrict__ ei, int E, int N, int* __restrict__ deg) {
  int i = blockIdx.x * blockDim.x + threadIdx.x;
  int Et = E + N;
  if (i >= Et) return;
  int d = (i < E) ? ei[E + i] : (i - E);
  atomicAdd(&deg[d], 1);
}

__global__ __launch_bounds__(1024) void k_scan(const int* __restrict__ deg,
                                               int* __restrict__ row_ptr,
                                               int* __restrict__ cursor, int n) {
  __shared__ int s[1024];
  int offset = 0;
  for (int base = 0; base < n; base += 1024) {
    int i = base + (int)threadIdx.x;
    int v = (i < n) ? deg[i] : 0;
    s[threadIdx.x] = v;
    __syncthreads();
    for (int d = 1; d < 1024; d <<= 1) {
      int add = ((int)threadIdx.x >= d) ? s[threadIdx.x - d] : 0;
      __syncthreads();
      s[threadIdx.x] += add;
      __syncthreads();
    }
    int incl = s[threadIdx.x];
    if (i < n) { row_ptr[i] = offset + incl - v; cursor[i] = offset + incl - v; }
    int total = s[1023];
    __syncthreads();
    offset += total;
  }
  if (threadIdx.x == 0) row_ptr[n] = offset;
}

__global__ void k_scatter(const int* __restrict__ ei, int E, int N,
                          int* __restrict__ cursor, int* __restrict__ csr_src) {
  int i = blockIdx.x * blockDim.x + threadIdx.x;
  int Et = E + N;
  if (i >= Et) return;
  int s = (i < E) ? ei[i] : (i - E);
  int d = (i < E) ? ei[E + i] : (i - E);
  int pos = atomicAdd(&cursor[d], 1);
  csr_src[pos] = s;
}

// ---------------- prep: w~[sel][h][k] = sum_c W1[k, h*128+c] * a[sel][h][c] ----------------

__global__ __launch_bounds__(256) void k_prep(const float* __restrict__ W1,
                                              const float* __restrict__ a_src,
                                              const float* __restrict__ a_dst,
                                              float* __restrict__ wsAll) {
  int gid = blockIdx.x * 256 + threadIdx.x;  // 0..4095
  int sel = gid >> 11;
  int id = gid & 2047;
  int h = id >> 7, k = id & 127;
  const float* av = sel ? a_dst : a_src;
  float sum = 0.f;
  const float* wrow = W1 + (size_t)k * 2048 + h * 128;
  const float* arow = av + h * 128;
#pragma unroll 4
  for (int c = 0; c < 128; ++c) sum += wrow[c] * arow[c];
  wsAll[gid] = sum;
}

// ---------------- layer-1 logits: als1/ald1[N,16] = x . w~ ----------------
// one wave per node; w~ staged in LDS.

__global__ __launch_bounds__(256) void k_al1x(const float* __restrict__ x,
                                              const float* __restrict__ wsAll,
                                              float* __restrict__ als, float* __restrict__ ald,
                                              int N) {
  __shared__ float ws_sh[4096];
#pragma unroll
  for (int i = 0; i < 4; ++i)
    ((float4*)ws_sh)[threadIdx.x + 256 * i] = ((const float4*)wsAll)[threadIdx.x + 256 * i];
  __syncthreads();
  int n = blockIdx.x * 4 + (threadIdx.x >> 6);
  int lane = threadIdx.x & 63;
  if (n >= N) return;
  float2 xv = *(const float2*)&x[(size_t)n * 128 + lane * 2];
#pragma unroll
  for (int h = 0; h < 16; ++h) {
    float2 ws2 = *(const float2*)&ws_sh[h * 128 + lane * 2];
    float2 wd2 = *(const float2*)&ws_sh[2048 + h * 128 + lane * 2];
    float ps = xv.x * ws2.x + xv.y * ws2.y;
    float pd = xv.x * wd2.x + xv.y * wd2.y;
    for (int off = 32; off; off >>= 1) {
      ps += __shfl_down(ps, off);
      pd += __shfl_down(pd, off);
    }
    if (lane == 0) { als[(size_t)n * 16 + h] = ps; ald[(size_t)n * 16 + h] = pd; }
  }
}

// ---------------- layer-1 attention in x-space ----------------
// one block (256 thr) per dst node. Online softmax per head, then gather x[src]
// (512 B/edge, L2-resident) and accumulate xagg[d,h,c] = sum alpha[h]*x[src][c].
// Output bf16 [N, 16*128].

__global__ __launch_bounds__(256) void k_attn1x(const float* __restrict__ x,
                                                const float* __restrict__ als,
                                                const float* __restrict__ ald,
                                                const int* __restrict__ row_ptr,
                                                const int* __restrict__ csr,
                                                __hip_bfloat16* __restrict__ xaggb,
                                                int N) {
  int d = blockIdx.x;
  int tid = threadIdx.x;
  int e0 = row_ptr[d];
  int deg = row_ptr[d + 1] - e0;

  __shared__ float red_m[16][17], red_s[16][17];
  __shared__ float m_h[16], iz_h[16];

  int hh = tid & 15, jj = tid >> 4;
  float aldh = ald[(size_t)d * 16 + hh];
  float mt = -1e30f, st = 0.f;
  for (int e = jj; e < deg; e += 16) {
    int s = csr[e0 + e];
    float l = leaky(als[(size_t)s * 16 + hh] + aldh);
    if (l > mt) { st = st * __expf(mt - l) + 1.f; mt = l; }
    else st += __expf(l - mt);
  }
  red_m[jj][hh] = mt;
  red_s[jj][hh] = st;
  __syncthreads();
  if (tid < 16) {
    float m = -1e30f;
#pragma unroll
    for (int k = 0; k < 16; ++k) m = fmaxf(m, red_m[k][tid]);
    float z = 0.f;
#pragma unroll
    for (int k = 0; k < 16; ++k) z += red_s[k][tid] * __expf(red_m[k][tid] - m);
    m_h[tid] = m;
    iz_h[tid] = 1.f / (z + 1e-16f);
  }
  __syncthreads();

  // phase C mapping: cg = tid&15 (channel group of 8), h = tid>>4 (head)
  int cg = tid & 15, h = tid >> 4;
  float acc[8] = {0.f, 0.f, 0.f, 0.f, 0.f, 0.f, 0.f, 0.f};
  __shared__ int srcb[16];
  __shared__ float alb[16][17];
  __shared__ float xs[16][132];
  for (int base = 0; base < deg; base += 16) {
    int nb = min(16, deg - base);
    __syncthreads();
    if (tid < nb) srcb[tid] = csr[e0 + base + tid];
    __syncthreads();
    if (tid < nb * 16) {
      int e = tid >> 4;  // hh == tid&15 matches aldh
      int s = srcb[e];
      float l = leaky(als[(size_t)s * 16 + hh] + aldh);
      alb[e][hh] = __expf(l - m_h[hh]) * iz_h[hh];
    }
    {
      int r = tid >> 4;
      if (r < nb) {
        const float4* xp = (const float4*)(x + (size_t)srcb[r] * 128) + (tid & 15) * 2;
        // need srcb visible: it is, after the sync below? -> load after sync
        (void)xp;
      }
    }
    __syncthreads();
    {
      int r = tid >> 4;
      if (r < nb) {
        const float4* xp = (const float4*)(x + (size_t)srcb[r] * 128) + (tid & 15) * 2;
        float4 v0 = xp[0], v1 = xp[1];
        *(float4*)&xs[r][(tid & 15) * 8] = v0;
        *(float4*)&xs[r][(tid & 15) * 8 + 4] = v1;
      }
    }
    __syncthreads();
    for (int e = 0; e < nb; ++e) {
      float a = alb[e][h];
      float4 v0 = *(const float4*)&xs[e][cg * 8];
      float4 v1 = *(const float4*)&xs[e][cg * 8 + 4];
      acc[0] += a * v0.x; acc[1] += a * v0.y; acc[2] += a * v0.z; acc[3] += a * v0.w;
      acc[4] += a * v1.x; acc[5] += a * v1.y; acc[6] += a * v1.z; acc[7] += a * v1.w;
    }
  }
  __hip_bfloat16 tmp[8];
#pragma unroll
  for (int i = 0; i < 8; ++i) tmp[i] = __float2bfloat16(acc[i]);
  *(uint4*)&xaggb[(size_t)d * 2048 + h * 128 + cg * 8] = *(uint4*)tmp;
}

// ---------------- per-head GEMM: h1act[N,2048] = ELU(xagg @blockdiag(W1) + b1) ----------------
// grid.x = 32: h = bx>>1, half = bx&1 (64 cols). BM=64, K=128, 256 thr, 4x4 microtile.

__global__ __launch_bounds__(256) void k_gemm1b(const __hip_bfloat16* __restrict__ xaggb,
                                                const float* __restrict__ W1,
                                                const float* __restrict__ b1,
                                                float* __restrict__ h1act, int N) {
  __shared__ float As[64][132];
  __shared__ float Bs[128][68];
  int bx = blockIdx.x;
  int h = bx >> 1, half = bx & 1;
  int col0 = h * 128 + half * 64;  // in [0,2048)
  int row0 = blockIdx.y * 64;
  int tid = threadIdx.x;
#pragma unroll
  for (int i = 0; i < 4; ++i) {  // A: 64 rows x 128 bf16 = 1024 chunks of 8 bf16
    int q = tid + 256 * i;
    int r = q >> 4, ck = q & 15;
    int gr = row0 + r;
    uint4 u = make_uint4(0u, 0u, 0u, 0u);
    if (gr < N) u = *(const uint4*)(xaggb + (size_t)gr * 2048 + h * 128 + ck * 8);
    float* ap = &As[r][ck * 8];
    ap[0] = __uint_as_float(u.x << 16);
    ap[1] = __uint_as_float(u.x & 0xffff0000u);
    ap[2] = __uint_as_float(u.y << 16);
    ap[3] = __uint_as_float(u.y & 0xffff0000u);
    ap[4] = __uint_as_float(u.z << 16);
    ap[5] = __uint_as_float(u.z & 0xffff0000u);
    ap[6] = __uint_as_float(u.w << 16);
    ap[7] = __uint_as_float(u.w & 0xffff0000u);
  }
#pragma unroll
  for (int i = 0; i < 8; ++i) {  // B: 128 rows x 64 cols fp32 = 2048 float4
    int q = tid + 256 * i;
    int r = q >> 4, c4 = q & 15;
    float4 v = *(const float4*)&W1[(size_t)r * 2048 + col0 + c4 * 4];
    *(float4*)&Bs[r][c4 * 4] = v;
  }
  __syncthreads();
  int tx = tid & 15, ty = tid >> 4;
  float acc[4][4] = {};
#pragma unroll 4
  for (int k = 0; k < 128; ++k) {
    float a0 = As[ty * 4 + 0][k];
    float a1 = As[ty * 4 + 1][k];
    float a2 = As[ty * 4 + 2][k];
    float a3 = As[ty * 4 + 3][k];
    float4 b = *(const float4*)&Bs[k][tx * 4];
    acc[0][0] += a0 * b.x; acc[0][1] += a0 * b.y; acc[0][2] += a0 * b.z; acc[0][3] += a0 * b.w;
    acc[1][0] += a1 * b.x; acc[1][1] += a1 * b.y; acc[1][2] += a1 * b.z; acc[1][3] += a1 * b.w;
    acc[2][0] += a2 * b.x; acc[2][1] += a2 * b.y; acc[2][2] += a2 * b.z; acc[2][3] += a2 * b.w;
    acc[3][0] += a3 * b.x; acc[3][1] += a3 * b.y; acc[3][2] += a3 * b.z; acc[3][3] += a3 * b.w;
  }
  float4 bias = *(const float4*)&b1[col0 + tx * 4];
#pragma unroll
  for (int i = 0; i < 4; ++i) {
    int gr = row0 + ty * 4 + i;
    if (gr < N) {
      float o0 = acc[i][0] + bias.x;
      float o1 = acc[i][1] + bias.y;
      float o2 = acc[i][2] + bias.z;
      float o3 = acc[i][3] + bias.w;
      o0 = o0 > 0.f ? o0 : expm1f(o0);
      o1 = o1 > 0.f ? o1 : expm1f(o1);
      o2 = o2 > 0.f ? o2 : expm1f(o2);
      o3 = o3 > 0.f ? o3 : expm1f(o3);
      *(float4*)&h1act[(size_t)gr * 2048 + col0 + tx * 4] = make_float4(o0, o1, o2, o3);
    }
  }
}

// ---------------- GEMM2: g[N,128] = h1act[N,2048] @ W2[2048,128] ----------------

__global__ __launch_bounds__(256) void k_gemm2(const float* __restrict__ A,
                                               const float* __restrict__ W,
                                               float* __restrict__ g, int N) {
  __shared__ float As[64][36];
  __shared__ float Bs[32][132];
  int row0 = blockIdx.x * 64;
  int tid = threadIdx.x;
  int tx = tid & 15, ty = tid >> 4;
  float acc[4][8] = {};
  for (int k0 = 0; k0 < 2048; k0 += 32) {
    __syncthreads();
#pragma unroll
    for (int i = 0; i < 2; ++i) {
      int f4i = tid + 256 * i;
      int r = f4i >> 3, c4 = f4i & 7;
      int gr = row0 + r;
      float4 v = make_float4(0.f, 0.f, 0.f, 0.f);
      if (gr < N) v = *(const float4*)&A[(size_t)gr * 2048 + k0 + c4 * 4];
      *(float4*)&As[r][c4 * 4] = v;
    }
#pragma unroll
    for (int i = 0; i < 4; ++i) {
      int f4i = tid + 256 * i;
      int r = f4i >> 5, c4 = f4i & 31;
      float4 v = *(const float4*)&W[(size_t)(k0 + r) * 128 + c4 * 4];
      *(float4*)&Bs[r][c4 * 4] = v;
    }
    __syncthreads();
#pragma unroll
    for (int kk = 0; kk < 32; ++kk) {
      float a0 = As[ty * 4 + 0][kk];
      float a1 = As[ty * 4 + 1][kk];
      float a2 = As[ty * 4 + 2][kk];
      float a3 = As[ty * 4 + 3][kk];
      float4 b0 = *(const float4*)&Bs[kk][tx * 8];
      float4 b1v = *(const float4*)&Bs[kk][tx * 8 + 4];
      acc[0][0] += a0 * b0.x; acc[0][1] += a0 * b0.y; acc[0][2] += a0 * b0.z; acc[0][3] += a0 * b0.w;
      acc[0][4] += a0 * b1v.x; acc[0][5] += a0 * b1v.y; acc[0][6] += a0 * b1v.z; acc[0][7] += a0 * b1v.w;
      acc[1][0] += a1 * b0.x; acc[1][1] += a1 * b0.y; acc[1][2] += a1 * b0.z; acc[1][3] += a1 * b0.w;
      acc[1][4] += a1 * b1v.x; acc[1][5] += a1 * b1v.y; acc[1][6] += a1 * b1v.z; acc[1][7] += a1 * b1v.w;
      acc[2][0] += a2 * b0.x; acc[2][1] += a2 * b0.y; acc[2][2] += a2 * b0.z; acc[2][3] += a2 * b0.w;
      acc[2][4] += a2 * b1v.x; acc[2][5] += a2 * b1v.y; acc[2][6] += a2 * b1v.z; acc[2][7] += a2 * b1v.w;
      acc[3][0] += a3 * b0.x; acc[3][1] += a3 * b0.y; acc[3][2] += a3 * b0.z; acc[3][3] += a3 * b0.w;
      acc[3][4] += a3 * b1v.x; acc[3][5] += a3 * b1v.y; acc[3][6] += a3 * b1v.z; acc[3][7] += a3 * b1v.w;
    }
  }
#pragma unroll
  for (int i = 0; i < 4; ++i) {
    int gr = row0 + ty * 4 + i;
    if (gr < N) {
      *(float4*)&g[(size_t)gr * 128 + tx * 8] =
          make_float4(acc[i][0], acc[i][1], acc[i][2], acc[i][3]);
      *(float4*)&g[(size_t)gr * 128 + tx * 8 + 4] =
          make_float4(acc[i][4], acc[i][5], acc[i][6], acc[i][7]);
    }
  }
}

// ---------------- attention logits layer 2 (1 head): one wave per node ----------------

__global__ __launch_bounds__(256) void k_al2(const float* __restrict__ g,
                                             const float* __restrict__ a_src,
                                             const float* __restrict__ a_dst,
                                             float* __restrict__ als, float* __restrict__ ald,
                                             int N) {
  int wid = (blockIdx.x * 256 + threadIdx.x) >> 6;
  int lane = threadIdx.x & 63;
  if (wid >= N) return;
  const float2 v = *(const float2*)(g + (size_t)wid * 128 + lane * 2);
  const float2 as = *(const float2*)(a_src + lane * 2);
  const float2 ad = *(const float2*)(a_dst + lane * 2);
  float ps = v.x * as.x + v.y * as.y;
  float pd = v.x * ad.x + v.y * ad.y;
  for (int off = 32; off; off >>= 1) {
    ps += __shfl_down(ps, off);
    pd += __shfl_down(pd, off);
  }
  if (lane == 0) { als[wid] = ps; ald[wid] = pd; }
}

// ---------------- layer-2 attention + aggregation + bias + classifier ----------------

__global__ __launch_bounds__(128) void k_attn2(const float* __restrict__ g,
                                               const float* __restrict__ als,
                                               const float* __restrict__ ald,
                                               const int* __restrict__ row_ptr,
                                               const int* __restrict__ csr,
                                               const float* __restrict__ b2,
                                               const float* __restrict__ Wc,
                                               const float* __restrict__ bc,
                                               float* __restrict__ out, int N) {
  int d = blockIdx.x;
  int tid = threadIdx.x;
  int e0 = row_ptr[d];
  int deg = row_ptr[d + 1] - e0;

  __shared__ float rm[128], rs[128];
  float aldd = ald[d];
  float mt = -1e30f, st = 0.f;
  for (int e = tid; e < deg; e += 128) {
    int s = csr[e0 + e];
    float l = leaky(als[s] + aldd);
    if (l > mt) { st = st * __expf(mt - l) + 1.f; mt = l; }
    else st += __expf(l - mt);
  }
  rm[tid] = mt; rs[tid] = st;
  __syncthreads();
  for (int off = 64; off; off >>= 1) {
    if (tid < off) {
      float m1 = rm[tid], s1 = rs[tid];
      float m2 = rm[tid + off], s2 = rs[tid + off];
      float m = fmaxf(m1, m2);
      rm[tid] = m;
      rs[tid] = s1 * __expf(m1 - m) + s2 * __expf(m2 - m);
    }
    __syncthreads();
  }
  float mh = rm[0];
  float invz = 1.f / (rs[0] + 1e-16f);
  __syncthreads();

  __shared__ int srcb[32];
  __shared__ float alb[32];
  float acc = 0.f;
  for (int base = 0; base < deg; base += 32) {
    int nb = min(32, deg - base);
    __syncthreads();
    if (tid < nb) {
      int s = csr[e0 + base + tid];
      srcb[tid] = s;
      float l = leaky(als[s] + aldd);
      alb[tid] = __expf(l - mh) * invz;
    }
    __syncthreads();
    for (int e = 0; e < nb; ++e) {
      acc += alb[e] * g[(size_t)srcb[e] * 128 + tid];
    }
  }
  float o = acc + b2[tid];
  float part = o * Wc[tid];
  __syncthreads();
  rs[tid] = part;
  __syncthreads();
  for (int off = 64; off; off >>= 1) {
    if (tid < off) rs[tid] += rs[tid + off];
    __syncthreads();
  }
  if (tid == 0) out[d] = rs[0] + bc[0];
}

// ---------------- launch ----------------

extern "C" void kernel_launch(void* const* d_in, const int* in_sizes, int n_in,
                              void* d_out, int out_size, void* d_ws, size_t ws_size,
                              hipStream_t stream) {
  const float* x      = (const float*)d_in[0];
  const int*   ei     = (const int*)d_in[1];
  const float* W1     = (const float*)d_in[2];
  const float* a_src1 = (const float*)d_in[3];
  const float* a_dst1 = (const float*)d_in[4];
  const float* b1     = (const float*)d_in[5];
  const float* W2     = (const float*)d_in[6];
  const float* a_src2 = (const float*)d_in[7];
  const float* a_dst2 = (const float*)d_in[8];
  const float* b2     = (const float*)d_in[9];
  const float* Wc     = (const float*)d_in[10];
  const float* bc     = (const float*)d_in[11];

  int N = in_sizes[0] / EMBED;
  int E = in_sizes[1] / 2;
  int Et = E + N;

  char* ws = (char*)d_ws;
  size_t off = 0;
  auto alloc = [&](size_t bytes) -> void* {
    void* p = ws + off;
    off += (bytes + 255) & ~(size_t)255;
    return p;
  };
  __hip_bfloat16* xaggb = (__hip_bfloat16*)alloc((size_t)N * 2048 * 2);
  float* h1act = (float*)alloc((size_t)N * 2048 * 4);
  float* wsAll = (float*)alloc(4096 * 4);
  float* als1  = (float*)alloc((size_t)N * 16 * 4);
  float* ald1  = (float*)alloc((size_t)N * 16 * 4);
  float* g     = (float*)alloc((size_t)N * 128 * 4);
  float* als2  = (float*)alloc((size_t)N * 4);
  float* ald2  = (float*)alloc((size_t)N * 4);
  int* deg     = (int*)alloc((size_t)N * 4);
  int* row_ptr = (int*)alloc((size_t)(N + 1) * 4);
  int* cursor  = (int*)alloc((size_t)N * 4);
  int* csr     = (int*)alloc((size_t)Et * 4);

  hipMemsetAsync(deg, 0, (size_t)N * 4, stream);
  k_hist<<<(Et + 255) / 256, 256, 0, stream>>>(ei, E, N, deg);
  k_scan<<<1, 1024, 0, stream>>>(deg, row_ptr, cursor, N);
  k_scatter<<<(Et + 255) / 256, 256, 0, stream>>>(ei, E, N, cursor, csr);

  k_prep<<<16, 256, 0, stream>>>(W1, a_src1, a_dst1, wsAll);
  k_al1x<<<(N + 3) / 4, 256, 0, stream>>>(x, wsAll, als1, ald1, N);
  k_attn1x<<<N, 256, 0, stream>>>(x, als1, ald1, row_ptr, csr, xaggb, N);

  k_gemm1b<<<dim3(32, (N + 63) / 64), 256, 0, stream>>>(xaggb, W1, b1, h1act, N);
  k_gemm2<<<(N + 63) / 64, 256, 0, stream>>>(h1act, W2, g, N);
  k_al2<<<(N + 3) / 4, 256, 0, stream>>>(g, a_src2, a_dst2, als2, ald2, N);
  k_attn2<<<N, 128, 0, stream>>>(g, als2, ald2, row_ptr, csr, b2, Wc, bc, (float*)d_out, N);
}

// Round 3
// 281.259 us; speedup vs baseline: 2.1934x; 1.7201x over previous
//
#include <hip/hip_runtime.h>
#include <hip/hip_bf16.h>

#define EMBED 128
#define HEADS 16
#define NEG 0.2f

typedef __attribute__((ext_vector_type(8))) short short8;
typedef __attribute__((ext_vector_type(4))) float floatx4;

static __device__ __forceinline__ float leaky(float x) { return x > 0.f ? x : NEG * x; }

static __device__ __forceinline__ short f2bf_bits(float f) {
  __hip_bfloat16 h = __float2bfloat16(f);
  union { __hip_bfloat16 b; short s; } u;
  u.b = h;
  return u.s;
}

// ---------------- CSR build ----------------

__global__ void k_hist(const int* __restrict__ ei, int E, int N, int* __restrict__ deg) {
  int i = blockIdx.x * blockDim.x + threadIdx.x;
  int Et = E + N;
  if (i >= Et) return;
  int d = (i < E) ? ei[E + i] : (i - E);
  atomicAdd(&deg[d], 1);
}

__global__ __launch_bounds__(1024) void k_scan(const int* __restrict__ deg,
                                               int* __restrict__ row_ptr,
                                               int* __restrict__ cursor, int n) {
  __shared__ int s[1024];
  int offset = 0;
  for (int base = 0; base < n; base += 1024) {
    int i = base + (int)threadIdx.x;
    int v = (i < n) ? deg[i] : 0;
    s[threadIdx.x] = v;
    __syncthreads();
    for (int d = 1; d < 1024; d <<= 1) {
      int add = ((int)threadIdx.x >= d) ? s[threadIdx.x - d] : 0;
      __syncthreads();
      s[threadIdx.x] += add;
      __syncthreads();
    }
    int incl = s[threadIdx.x];
    if (i < n) { row_ptr[i] = offset + incl - v; cursor[i] = offset + incl - v; }
    int total = s[1023];
    __syncthreads();
    offset += total;
  }
  if (threadIdx.x == 0) row_ptr[n] = offset;
}

__global__ void k_scatter(const int* __restrict__ ei, int E, int N,
                          int* __restrict__ cursor, int* __restrict__ csr_src) {
  int i = blockIdx.x * blockDim.x + threadIdx.x;
  int Et = E + N;
  if (i >= Et) return;
  int s = (i < E) ? ei[i] : (i - E);
  int d = (i < E) ? ei[E + i] : (i - E);
  int pos = atomicAdd(&cursor[d], 1);
  csr_src[pos] = s;
}

// ---------------- prep: w~[sel][h][k] = sum_c W1[k, h*128+c] * a[sel][h][c] ----------------

__global__ __launch_bounds__(256) void k_prep(const float* __restrict__ W1,
                                              const float* __restrict__ a_src,
                                              const float* __restrict__ a_dst,
                                              float* __restrict__ wsAll) {
  int gid = blockIdx.x * 256 + threadIdx.x;  // 0..4095
  int sel = gid >> 11;
  int id = gid & 2047;
  int h = id >> 7, k = id & 127;
  const float* av = sel ? a_dst : a_src;
  float sum = 0.f;
  const float* wrow = W1 + (size_t)k * 2048 + h * 128;
  const float* arow = av + h * 128;
#pragma unroll 4
  for (int c = 0; c < 128; ++c) sum += wrow[c] * arow[c];
  wsAll[gid] = sum;
}

// ---------------- prep2a: W1T hi/lo bf16, layout [h][j][c] ----------------

__global__ __launch_bounds__(256) void k_prep2a(const float* __restrict__ W1,
                                                short* __restrict__ hi,
                                                short* __restrict__ lo) {
  int gid = blockIdx.x * 256 + threadIdx.x;  // 0..262143 = h*16384 + j*128 + c
  int h = gid >> 14;
  int j = (gid >> 7) & 127;
  int c = gid & 127;
  float wv = W1[(size_t)c * 2048 + h * 128 + j];
  __hip_bfloat16 hb = __float2bfloat16(wv);
  float hf = __bfloat162float(hb);
  hi[gid] = f2bf_bits(wv);
  lo[gid] = f2bf_bits(wv - hf);
}

// ---------------- prep2b: u vectors = W2 @ {Wc, a_src2, a_dst2}, + cconst ----------------

__global__ __launch_bounds__(256) void k_prep2b(const float* __restrict__ W2,
                                                const float* __restrict__ a_src2,
                                                const float* __restrict__ a_dst2,
                                                const float* __restrict__ Wc,
                                                const float* __restrict__ b2,
                                                const float* __restrict__ bc,
                                                float* __restrict__ uvec,
                                                float* __restrict__ cconst) {
  int gid = blockIdx.x * 256 + threadIdx.x;
  if (gid < 6144) {
    int sel = gid >> 11;  // 0: Wc, 1: a_src2, 2: a_dst2
    int k = gid & 2047;
    const float* v = sel == 0 ? Wc : (sel == 1 ? a_src2 : a_dst2);
    const float* wrow = W2 + (size_t)k * 128;
    float s = 0.f;
#pragma unroll 4
    for (int j = 0; j < 128; ++j) s += wrow[j] * v[j];
    uvec[gid] = s;
  } else if (gid == 6144) {
    float s = 0.f;
    for (int j = 0; j < 128; ++j) s += b2[j] * Wc[j];
    *cconst = s + bc[0];
  }
}

// ---------------- layer-1 logits: als1/ald1[N,16] = x . w~ ----------------

__global__ __launch_bounds__(256) void k_al1x(const float* __restrict__ x,
                                              const float* __restrict__ wsAll,
                                              float* __restrict__ als, float* __restrict__ ald,
                                              int N) {
  __shared__ float ws_sh[4096];
#pragma unroll
  for (int i = 0; i < 4; ++i)
    ((float4*)ws_sh)[threadIdx.x + 256 * i] = ((const float4*)wsAll)[threadIdx.x + 256 * i];
  __syncthreads();
  int n = blockIdx.x * 4 + (threadIdx.x >> 6);
  int lane = threadIdx.x & 63;
  if (n >= N) return;
  float2 xv = *(const float2*)&x[(size_t)n * 128 + lane * 2];
#pragma unroll
  for (int h = 0; h < 16; ++h) {
    float2 ws2 = *(const float2*)&ws_sh[h * 128 + lane * 2];
    float2 wd2 = *(const float2*)&ws_sh[2048 + h * 128 + lane * 2];
    float ps = xv.x * ws2.x + xv.y * ws2.y;
    float pd = xv.x * wd2.x + xv.y * wd2.y;
    for (int off = 32; off; off >>= 1) {
      ps += __shfl_down(ps, off);
      pd += __shfl_down(pd, off);
    }
    if (lane == 0) { als[(size_t)n * 16 + h] = ps; ald[(size_t)n * 16 + h] = pd; }
  }
}

// ---------------- layer-1 attention in x-space -> xagg bf16 [N,16*128] ----------------

__global__ __launch_bounds__(256) void k_attn1x(const float* __restrict__ x,
                                                const float* __restrict__ als,
                                                const float* __restrict__ ald,
                                                const int* __restrict__ row_ptr,
                                                const int* __restrict__ csr,
                                                __hip_bfloat16* __restrict__ xaggb,
                                                int N) {
  int d = blockIdx.x;
  int tid = threadIdx.x;
  int e0 = row_ptr[d];
  int deg = row_ptr[d + 1] - e0;

  __shared__ float red_m[16][17], red_s[16][17];
  __shared__ float m_h[16], iz_h[16];

  int hh = tid & 15, jj = tid >> 4;
  float aldh = ald[(size_t)d * 16 + hh];
  float mt = -1e30f, st = 0.f;
  for (int e = jj; e < deg; e += 16) {
    int s = csr[e0 + e];
    float l = leaky(als[(size_t)s * 16 + hh] + aldh);
    if (l > mt) { st = st * __expf(mt - l) + 1.f; mt = l; }
    else st += __expf(l - mt);
  }
  red_m[jj][hh] = mt;
  red_s[jj][hh] = st;
  __syncthreads();
  if (tid < 16) {
    float m = -1e30f;
#pragma unroll
    for (int k = 0; k < 16; ++k) m = fmaxf(m, red_m[k][tid]);
    float z = 0.f;
#pragma unroll
    for (int k = 0; k < 16; ++k) z += red_s[k][tid] * __expf(red_m[k][tid] - m);
    m_h[tid] = m;
    iz_h[tid] = 1.f / (z + 1e-16f);
  }
  __syncthreads();

  int cg = tid & 15, h = tid >> 4;
  float acc[8] = {0.f, 0.f, 0.f, 0.f, 0.f, 0.f, 0.f, 0.f};
  __shared__ int srcb[16];
  __shared__ float alb[16][17];
  __shared__ float xs[16][132];
  for (int base = 0; base < deg; base += 16) {
    int nb = min(16, deg - base);
    __syncthreads();
    if (tid < nb) srcb[tid] = csr[e0 + base + tid];
    __syncthreads();
    if (tid < nb * 16) {
      int e = tid >> 4;
      int s = srcb[e];
      float l = leaky(als[(size_t)s * 16 + hh] + aldh);
      alb[e][hh] = __expf(l - m_h[hh]) * iz_h[hh];
    }
    {
      int r = tid >> 4;
      if (r < nb) {
        const float4* xp = (const float4*)(x + (size_t)srcb[r] * 128) + (tid & 15) * 2;
        float4 v0 = xp[0], v1 = xp[1];
        *(float4*)&xs[r][(tid & 15) * 8] = v0;
        *(float4*)&xs[r][(tid & 15) * 8 + 4] = v1;
      }
    }
    __syncthreads();
    for (int e = 0; e < nb; ++e) {
      float a = alb[e][h];
      float4 v0 = *(const float4*)&xs[e][cg * 8];
      float4 v1 = *(const float4*)&xs[e][cg * 8 + 4];
      acc[0] += a * v0.x; acc[1] += a * v0.y; acc[2] += a * v0.z; acc[3] += a * v0.w;
      acc[4] += a * v1.x; acc[5] += a * v1.y; acc[6] += a * v1.z; acc[7] += a * v1.w;
    }
  }
  __hip_bfloat16 tmp[8];
#pragma unroll
  for (int i = 0; i < 8; ++i) tmp[i] = __float2bfloat16(acc[i]);
  *(uint4*)&xaggb[(size_t)d * 2048 + h * 128 + cg * 8] = *(uint4*)tmp;
}

// ---------------- fused: h1act = ELU(xagg @ bdiag(W1) + b1); contract with u vectors ----------------
// grid (ceil(N/32), 4). 256 thr = 4 waves; wave w handles head by*4+w for 32 nodes.
// MFMA 16x16x32 bf16, W1 split hi/lo (2 MFMAs = ~fp32 quality). No LDS in main loop.

__global__ __launch_bounds__(256) void k_fused(const __hip_bfloat16* __restrict__ xaggb,
                                               const short* __restrict__ w1t_hi,
                                               const short* __restrict__ w1t_lo,
                                               const float* __restrict__ b1,
                                               const float* __restrict__ uvec,
                                               float* __restrict__ partc,
                                               float* __restrict__ parts,
                                               float* __restrict__ partd,
                                               int N) {
  __shared__ float sh[2048];  // [0..511]=b1 seg, [512..]=uc seg, [1024..]=us seg, [1536..]=ud seg
  int tid = threadIdx.x;
  int by = blockIdx.y;
  int base = by * 512;
#pragma unroll
  for (int i = 0; i < 8; ++i) {
    int idx = tid + 256 * i;
    int arr = idx >> 9, off = idx & 511;
    sh[idx] = (arr == 0) ? b1[base + off] : uvec[(arr - 1) * 2048 + base + off];
  }
  __syncthreads();

  int w = tid >> 6, lane = tid & 63;
  int h = by * 4 + w;
  int quad = lane >> 4, l15 = lane & 15;
  int n0 = blockIdx.x * 32;

  floatx4 acc[2][8];
#pragma unroll
  for (int mt = 0; mt < 2; ++mt)
#pragma unroll
    for (int jt = 0; jt < 8; ++jt) acc[mt][jt] = (floatx4)(0.f);

  const short* bh = w1t_hi + h * 16384;
  const short* bl = w1t_lo + h * 16384;
  int na = n0 + l15, nb = n0 + 16 + l15;
  const __hip_bfloat16* pa = xaggb + (size_t)na * 2048 + h * 128;
  const __hip_bfloat16* pb = xaggb + (size_t)nb * 2048 + h * 128;

  for (int ks = 0; ks < 4; ++ks) {
    int koff = ks * 32 + quad * 8;
    union { uint4 u; short8 s; } ua, ub;
    if (na < N) ua.u = *(const uint4*)(pa + koff); else ua.u = make_uint4(0u, 0u, 0u, 0u);
    if (nb < N) ub.u = *(const uint4*)(pb + koff); else ub.u = make_uint4(0u, 0u, 0u, 0u);
#pragma unroll
    for (int jt = 0; jt < 8; ++jt) {
      int j = jt * 16 + l15;
      union { uint4 u; short8 s; } wh, wl;
      wh.u = *(const uint4*)(bh + j * 128 + koff);
      wl.u = *(const uint4*)(bl + j * 128 + koff);
      acc[0][jt] = __builtin_amdgcn_mfma_f32_16x16x32_bf16(ua.s, wh.s, acc[0][jt], 0, 0, 0);
      acc[1][jt] = __builtin_amdgcn_mfma_f32_16x16x32_bf16(ub.s, wh.s, acc[1][jt], 0, 0, 0);
      acc[0][jt] = __builtin_amdgcn_mfma_f32_16x16x32_bf16(ua.s, wl.s, acc[0][jt], 0, 0, 0);
      acc[1][jt] = __builtin_amdgcn_mfma_f32_16x16x32_bf16(ub.s, wl.s, acc[1][jt], 0, 0, 0);
    }
  }

#pragma unroll
  for (int mt = 0; mt < 2; ++mt) {
#pragma unroll
    for (int r = 0; r < 4; ++r) {
      int node = n0 + mt * 16 + quad * 4 + r;
      float pc = 0.f, ps = 0.f, pd = 0.f;
#pragma unroll
      for (int jt = 0; jt < 8; ++jt) {
        int jl = w * 128 + jt * 16 + l15;
        float v = acc[mt][jt][r] + sh[jl];
        float e = v > 0.f ? v : expm1f(v);
        pc += e * sh[512 + jl];
        ps += e * sh[1024 + jl];
        pd += e * sh[1536 + jl];
      }
#pragma unroll
      for (int off = 1; off <= 8; off <<= 1) {
        pc += __shfl_xor(pc, off);
        ps += __shfl_xor(ps, off);
        pd += __shfl_xor(pd, off);
      }
      if (l15 == 0 && node < N) {
        atomicAdd(&partc[node], pc);
        atomicAdd(&parts[node], ps);
        atomicAdd(&partd[node], pd);
      }
    }
  }
}

// ---------------- layer-2 attention, all-scalar: out[d] = sum alpha*c[s] + cconst ----------------

__global__ __launch_bounds__(256) void k_attn2s(const float* __restrict__ partc,
                                                const float* __restrict__ parts,
                                                const float* __restrict__ partd,
                                                const int* __restrict__ row_ptr,
                                                const int* __restrict__ csr,
                                                const float* __restrict__ cconst,
                                                float* __restrict__ out, int N) {
  int w = threadIdx.x >> 6, lane = threadIdx.x & 63;
  int d = blockIdx.x * 4 + w;
  if (d >= N) return;
  int e0 = row_ptr[d], deg = row_ptr[d + 1] - e0;
  float aldd = partd[d];
  float mt = -1e30f, st = 0.f;
  for (int e = lane; e < deg; e += 64) {
    int s = csr[e0 + e];
    float l = leaky(parts[s] + aldd);
    if (l > mt) { st = st * __expf(mt - l) + 1.f; mt = l; }
    else st += __expf(l - mt);
  }
#pragma unroll
  for (int off = 32; off; off >>= 1) {
    float m2 = __shfl_xor(mt, off);
    float s2 = __shfl_xor(st, off);
    float m = fmaxf(mt, m2);
    st = st * __expf(mt - m) + s2 * __expf(m2 - m);
    mt = m;
  }
  float invz = 1.f / (st + 1e-16f);
  float acc = 0.f;
  for (int e = lane; e < deg; e += 64) {
    int s = csr[e0 + e];
    float l = leaky(parts[s] + aldd);
    acc += __expf(l - mt) * partc[s];
  }
#pragma unroll
  for (int off = 32; off; off >>= 1) acc += __shfl_xor(acc, off);
  if (lane == 0) out[d] = acc * invz + cconst[0];
}

// ---------------- launch ----------------

extern "C" void kernel_launch(void* const* d_in, const int* in_sizes, int n_in,
                              void* d_out, int out_size, void* d_ws, size_t ws_size,
                              hipStream_t stream) {
  const float* x      = (const float*)d_in[0];
  const int*   ei     = (const int*)d_in[1];
  const float* W1     = (const float*)d_in[2];
  const float* a_src1 = (const float*)d_in[3];
  const float* a_dst1 = (const float*)d_in[4];
  const float* b1     = (const float*)d_in[5];
  const float* W2     = (const float*)d_in[6];
  const float* a_src2 = (const float*)d_in[7];
  const float* a_dst2 = (const float*)d_in[8];
  const float* b2     = (const float*)d_in[9];
  const float* Wc     = (const float*)d_in[10];
  const float* bc     = (const float*)d_in[11];

  int N = in_sizes[0] / EMBED;
  int E = in_sizes[1] / 2;
  int Et = E + N;

  char* ws = (char*)d_ws;
  size_t off = 0;
  auto alloc = [&](size_t bytes) -> void* {
    void* p = ws + off;
    off += (bytes + 255) & ~(size_t)255;
    return p;
  };
  __hip_bfloat16* xaggb = (__hip_bfloat16*)alloc((size_t)N * 2048 * 2);
  short* w1t_hi = (short*)alloc((size_t)262144 * 2);
  short* w1t_lo = (short*)alloc((size_t)262144 * 2);
  float* wsAll  = (float*)alloc(4096 * 4);
  float* uvec   = (float*)alloc(6144 * 4);
  float* cconst = (float*)alloc(256);
  float* als1   = (float*)alloc((size_t)N * 16 * 4);
  float* ald1   = (float*)alloc((size_t)N * 16 * 4);
  float* part   = (float*)alloc((size_t)3 * N * 4);
  float* partc  = part;
  float* parts  = part + N;
  float* partd  = part + 2 * N;
  int* deg      = (int*)alloc((size_t)N * 4);
  int* row_ptr  = (int*)alloc((size_t)(N + 1) * 4);
  int* cursor   = (int*)alloc((size_t)N * 4);
  int* csr      = (int*)alloc((size_t)Et * 4);

  hipMemsetAsync(deg, 0, (size_t)N * 4, stream);
  hipMemsetAsync(part, 0, (size_t)3 * N * 4, stream);

  k_hist<<<(Et + 255) / 256, 256, 0, stream>>>(ei, E, N, deg);
  k_scan<<<1, 1024, 0, stream>>>(deg, row_ptr, cursor, N);
  k_scatter<<<(Et + 255) / 256, 256, 0, stream>>>(ei, E, N, cursor, csr);

  k_prep<<<16, 256, 0, stream>>>(W1, a_src1, a_dst1, wsAll);
  k_prep2a<<<1024, 256, 0, stream>>>(W1, w1t_hi, w1t_lo);
  k_prep2b<<<25, 256, 0, stream>>>(W2, a_src2, a_dst2, Wc, b2, bc, uvec, cconst);

  k_al1x<<<(N + 3) / 4, 256, 0, stream>>>(x, wsAll, als1, ald1, N);
  k_attn1x<<<N, 256, 0, stream>>>(x, als1, ald1, row_ptr, csr, xaggb, N);

  k_fused<<<dim3((N + 31) / 32, 4), 256, 0, stream>>>(xaggb, w1t_hi, w1t_lo, b1, uvec,
                                                      partc, parts, partd, N);
  k_attn2s<<<(N + 3) / 4, 256, 0, stream>>>(partc, parts, partd, row_ptr, csr, cconst,
                                            (float*)d_out, N);
}

// Round 4
// 261.593 us; speedup vs baseline: 2.3583x; 1.0752x over previous
//
#include <hip/hip_runtime.h>
#include <hip/hip_bf16.h>

#define EMBED 128
#define HEADS 16
#define NEG 0.2f

typedef __attribute__((ext_vector_type(8))) short short8;
typedef __attribute__((ext_vector_type(4))) float floatx4;

static __device__ __forceinline__ float leaky(float x) { return x > 0.f ? x : NEG * x; }

static __device__ __forceinline__ short f2bf_bits(float f) {
  __hip_bfloat16 h = __float2bfloat16(f);
  union { __hip_bfloat16 b; short s; } u;
  u.b = h;
  return u.s;
}

// ---------------- CSR build ----------------

__global__ void k_hist(const int* __restrict__ ei, int E, int N, int* __restrict__ deg) {
  int i = blockIdx.x * blockDim.x + threadIdx.x;
  int Et = E + N;
  if (i >= Et) return;
  int d = (i < E) ? ei[E + i] : (i - E);
  atomicAdd(&deg[d], 1);
}

__global__ __launch_bounds__(256) void k_scan1(const int* __restrict__ deg,
                                               int* __restrict__ excl,
                                               int* __restrict__ bsum, int n) {
  __shared__ int s[256];
  int i = blockIdx.x * 256 + threadIdx.x;
  int v = (i < n) ? deg[i] : 0;
  s[threadIdx.x] = v;
  __syncthreads();
  for (int d = 1; d < 256; d <<= 1) {
    int add = ((int)threadIdx.x >= d) ? s[threadIdx.x - d] : 0;
    __syncthreads();
    s[threadIdx.x] += add;
    __syncthreads();
  }
  if (i < n) excl[i] = s[threadIdx.x] - v;
  if (threadIdx.x == 255) bsum[blockIdx.x] = s[255];
}

__global__ void k_scan2(int* __restrict__ bsum, int nb) {
  if (threadIdx.x == 0 && blockIdx.x == 0) {
    int acc = 0;
    for (int i = 0; i < nb; ++i) { int v = bsum[i]; bsum[i] = acc; acc += v; }
  }
}

__global__ __launch_bounds__(256) void k_scan3(const int* __restrict__ deg,
                                               const int* __restrict__ excl,
                                               const int* __restrict__ bsum,
                                               int* __restrict__ row_ptr,
                                               int* __restrict__ cursor, int n) {
  int i = blockIdx.x * 256 + threadIdx.x;
  if (i < n) {
    int r = excl[i] + bsum[blockIdx.x];
    row_ptr[i] = r;
    cursor[i] = r;
    if (i == n - 1) row_ptr[n] = r + deg[i];
  }
}

__global__ void k_scatter(const int* __restrict__ ei, int E, int N,
                          int* __restrict__ cursor, int* __restrict__ csr_src) {
  int i = blockIdx.x * blockDim.x + threadIdx.x;
  int Et = E + N;
  if (i >= Et) return;
  int s = (i < E) ? ei[i] : (i - E);
  int d = (i < E) ? ei[E + i] : (i - E);
  int pos = atomicAdd(&cursor[d], 1);
  csr_src[pos] = s;
}

// ---------------- merged prep: w~ vectors (layer1 logits) + u vectors (layer2 folded) ----------------

__global__ __launch_bounds__(256) void k_prepAll(const float* __restrict__ W1,
                                                 const float* __restrict__ a_src1,
                                                 const float* __restrict__ a_dst1,
                                                 const float* __restrict__ W2,
                                                 const float* __restrict__ a_src2,
                                                 const float* __restrict__ a_dst2,
                                                 const float* __restrict__ Wc,
                                                 const float* __restrict__ b2,
                                                 const float* __restrict__ bc,
                                                 float* __restrict__ wsAll,
                                                 float* __restrict__ uvec,
                                                 float* __restrict__ cconst) {
  int gid = blockIdx.x * 256 + threadIdx.x;
  if (gid < 4096) {
    int sel = gid >> 11;
    int id = gid & 2047;
    int h = id >> 7, k = id & 127;
    const float* av = sel ? a_dst1 : a_src1;
    float sum = 0.f;
    const float* wrow = W1 + (size_t)k * 2048 + h * 128;
    const float* arow = av + h * 128;
#pragma unroll 4
    for (int c = 0; c < 128; ++c) sum += wrow[c] * arow[c];
    wsAll[gid] = sum;
  } else if (gid < 10240) {
    int g = gid - 4096;
    int sel = g >> 11;  // 0: Wc, 1: a_src2, 2: a_dst2
    int k = g & 2047;
    const float* v = sel == 0 ? Wc : (sel == 1 ? a_src2 : a_dst2);
    const float* wrow = W2 + (size_t)k * 128;
    float s = 0.f;
#pragma unroll 4
    for (int j = 0; j < 128; ++j) s += wrow[j] * v[j];
    uvec[g] = s;
  } else if (gid == 10240) {
    float s = 0.f;
    for (int j = 0; j < 128; ++j) s += b2[j] * Wc[j];
    *cconst = s + bc[0];
  }
}

// ---------------- W1^T hi/lo bf16 via LDS tile transpose: layout [h][j][c] ----------------

__global__ __launch_bounds__(256) void k_prep2aT(const float* __restrict__ W1,
                                                 short* __restrict__ hi,
                                                 short* __restrict__ lo) {
  __shared__ float tile[64][65];
  int h = blockIdx.x;
  int c0 = blockIdx.y * 64;
  int j0 = blockIdx.z * 64;
  int t = threadIdx.x;
#pragma unroll
  for (int i = 0; i < 4; ++i) {
    int idx4 = i * 256 + t;
    int c = idx4 >> 4, j4 = idx4 & 15;
    float4 v = *(const float4*)&W1[(size_t)(c0 + c) * 2048 + h * 128 + j0 + j4 * 4];
    tile[c][j4 * 4 + 0] = v.x;
    tile[c][j4 * 4 + 1] = v.y;
    tile[c][j4 * 4 + 2] = v.z;
    tile[c][j4 * 4 + 3] = v.w;
  }
  __syncthreads();
#pragma unroll
  for (int i = 0; i < 4; ++i) {
    int idx = i * 256 + t;
    int j = idx >> 4, c4 = idx & 15;
    unsigned short vh[4], vl[4];
#pragma unroll
    for (int ii = 0; ii < 4; ++ii) {
      float wv = tile[c4 * 4 + ii][j];
      short hb = f2bf_bits(wv);
      float hf = __uint_as_float(((unsigned int)(unsigned short)hb) << 16);
      vh[ii] = (unsigned short)hb;
      vl[ii] = (unsigned short)f2bf_bits(wv - hf);
    }
    size_t o = (size_t)h * 16384 + (size_t)(j0 + j) * 128 + c0 + c4 * 4;
    *(ushort4*)&hi[o] = make_ushort4(vh[0], vh[1], vh[2], vh[3]);
    *(ushort4*)&lo[o] = make_ushort4(vl[0], vl[1], vl[2], vl[3]);
  }
}

// ---------------- layer-1 logits: als1/ald1[N,16] = x . w~ ----------------

__global__ __launch_bounds__(256) void k_al1x(const float* __restrict__ x,
                                              const float* __restrict__ wsAll,
                                              float* __restrict__ als, float* __restrict__ ald,
                                              int N) {
  __shared__ float ws_sh[4096];
#pragma unroll
  for (int i = 0; i < 4; ++i)
    ((float4*)ws_sh)[threadIdx.x + 256 * i] = ((const float4*)wsAll)[threadIdx.x + 256 * i];
  __syncthreads();
  int n = blockIdx.x * 4 + (threadIdx.x >> 6);
  int lane = threadIdx.x & 63;
  if (n >= N) return;
  float2 xv = *(const float2*)&x[(size_t)n * 128 + lane * 2];
#pragma unroll
  for (int h = 0; h < 16; ++h) {
    float2 ws2 = *(const float2*)&ws_sh[h * 128 + lane * 2];
    float2 wd2 = *(const float2*)&ws_sh[2048 + h * 128 + lane * 2];
    float ps = xv.x * ws2.x + xv.y * ws2.y;
    float pd = xv.x * wd2.x + xv.y * wd2.y;
    for (int off = 32; off; off >>= 1) {
      ps += __shfl_down(ps, off);
      pd += __shfl_down(pd, off);
    }
    if (lane == 0) { als[(size_t)n * 16 + h] = ps; ald[(size_t)n * 16 + h] = pd; }
  }
}

// ---------------- z (softmax denom, no max-subtraction): iz[d,h] = 1/(sum exp + 1e-16) ----------------

__global__ __launch_bounds__(256) void k_z(const float* __restrict__ als,
                                           const float* __restrict__ ald,
                                           const int* __restrict__ row_ptr,
                                           const int* __restrict__ csr,
                                           float* __restrict__ iz, int N) {
  int gid = blockIdx.x * 256 + threadIdx.x;
  if (gid >= N * 16) return;
  int d = gid >> 4, h = gid & 15;
  int e0 = row_ptr[d], e1 = row_ptr[d + 1];
  float aldh = ald[gid];
  float z = 0.f;
  for (int e = e0; e < e1; ++e) {
    int s = csr[e];
    z += __expf(leaky(als[(size_t)s * 16 + h] + aldh));
  }
  iz[gid] = 1.f / (z + 1e-16f);
}

// ---------------- layer-1 attention in x-space -> xagg bf16 [N,16*128] ----------------

__global__ __launch_bounds__(256) void k_attn1b(const float* __restrict__ x,
                                                const float* __restrict__ als,
                                                const float* __restrict__ ald,
                                                const float* __restrict__ iz,
                                                const int* __restrict__ row_ptr,
                                                const int* __restrict__ csr,
                                                __hip_bfloat16* __restrict__ xaggb,
                                                int N) {
  int d = blockIdx.x;
  int tid = threadIdx.x;
  int e0 = row_ptr[d];
  int deg = row_ptr[d + 1] - e0;

  __shared__ float ald_sh[16], iz_sh[16];
  if (tid < 16) { ald_sh[tid] = ald[(size_t)d * 16 + tid]; iz_sh[tid] = iz[(size_t)d * 16 + tid]; }
  __syncthreads();

  int hh = tid & 15;
  float aldh = ald_sh[hh], izh = iz_sh[hh];
  int cg = tid & 15, h = tid >> 4;
  float acc[8] = {0.f, 0.f, 0.f, 0.f, 0.f, 0.f, 0.f, 0.f};
  __shared__ int srcb[16];
  __shared__ float alb[16][17];
  __shared__ float xs[16][132];
  for (int base = 0; base < deg; base += 16) {
    int nb = min(16, deg - base);
    __syncthreads();
    if (tid < nb) srcb[tid] = csr[e0 + base + tid];
    __syncthreads();
    if (tid < nb * 16) {
      int e = tid >> 4;
      float l = leaky(als[(size_t)srcb[e] * 16 + hh] + aldh);
      alb[e][hh] = __expf(l) * izh;
    }
    {
      int r = tid >> 4;
      if (r < nb) {
        const float4* xp = (const float4*)(x + (size_t)srcb[r] * 128) + (tid & 15) * 2;
        float4 v0 = xp[0], v1 = xp[1];
        *(float4*)&xs[r][(tid & 15) * 8] = v0;
        *(float4*)&xs[r][(tid & 15) * 8 + 4] = v1;
      }
    }
    __syncthreads();
    for (int e = 0; e < nb; ++e) {
      float a = alb[e][h];
      float4 v0 = *(const float4*)&xs[e][cg * 8];
      float4 v1 = *(const float4*)&xs[e][cg * 8 + 4];
      acc[0] += a * v0.x; acc[1] += a * v0.y; acc[2] += a * v0.z; acc[3] += a * v0.w;
      acc[4] += a * v1.x; acc[5] += a * v1.y; acc[6] += a * v1.z; acc[7] += a * v1.w;
    }
  }
  __hip_bfloat16 tmp[8];
#pragma unroll
  for (int i = 0; i < 8; ++i) tmp[i] = __float2bfloat16(acc[i]);
  *(uint4*)&xaggb[(size_t)d * 2048 + h * 128 + cg * 8] = *(uint4*)tmp;
}

// ---------------- fused: ELU(xagg @ bdiag(W1) + b1) contracted with u vectors ----------------
// grid (ceil(N/32), 4). Block stages A (32 nodes x 4 heads = 32KB, 16B/row pad) in LDS;
// wave w = head by*4+w, 2 m-tiles of 16 nodes; B (W1^T hi/lo bf16) streamed from L2.

__global__ __launch_bounds__(256) void k_fused(const __hip_bfloat16* __restrict__ xaggb,
                                               const short* __restrict__ w1t_hi,
                                               const short* __restrict__ w1t_lo,
                                               const float* __restrict__ b1,
                                               const float* __restrict__ uvec,
                                               float* __restrict__ partc,
                                               float* __restrict__ parts,
                                               float* __restrict__ partd,
                                               int N) {
  __shared__ float sh[2048];
  __shared__ __align__(16) char Ash[32 * 1040];
  int tid = threadIdx.x;
  int by = blockIdx.y;
  int base = by * 512;
#pragma unroll
  for (int i = 0; i < 8; ++i) {
    int idx = tid + 256 * i;
    int arr = idx >> 9, off = idx & 511;
    sh[idx] = (arr == 0) ? b1[base + off] : uvec[(arr - 1) * 2048 + base + off];
  }
  int n0 = blockIdx.x * 32;
#pragma unroll
  for (int i = 0; i < 8; ++i) {
    int flat = i * 4096 + tid * 16;  // byte index in unpadded 32KB A block
    int row = flat >> 10;
    int within = flat & 1023;
    int node = n0 + row;
    if (node >= N) node = N - 1;
    uint4 v = *(const uint4*)((const char*)xaggb + (size_t)node * 4096 + by * 1024 + within);
    *(uint4*)(Ash + row * 1040 + within) = v;
  }
  __syncthreads();

  int w = tid >> 6, lane = tid & 63;
  int h = by * 4 + w;
  int quad = lane >> 4, l15 = lane & 15;

  floatx4 acc[2][8];
#pragma unroll
  for (int mt = 0; mt < 2; ++mt)
#pragma unroll
    for (int jt = 0; jt < 8; ++jt) acc[mt][jt] = (floatx4)(0.f);

  const short* bh = w1t_hi + h * 16384;
  const short* bl = w1t_lo + h * 16384;

  for (int ks = 0; ks < 4; ++ks) {
    short8 ua = *(const short8*)(Ash + l15 * 1040 + w * 256 + ks * 64 + quad * 16);
    short8 ub = *(const short8*)(Ash + (16 + l15) * 1040 + w * 256 + ks * 64 + quad * 16);
    int koff = ks * 32 + quad * 8;
#pragma unroll
    for (int jt = 0; jt < 8; ++jt) {
      int j = jt * 16 + l15;
      union { uint4 u; short8 s; } wh, wl;
      wh.u = *(const uint4*)(bh + j * 128 + koff);
      wl.u = *(const uint4*)(bl + j * 128 + koff);
      acc[0][jt] = __builtin_amdgcn_mfma_f32_16x16x32_bf16(ua, wh.s, acc[0][jt], 0, 0, 0);
      acc[1][jt] = __builtin_amdgcn_mfma_f32_16x16x32_bf16(ub, wh.s, acc[1][jt], 0, 0, 0);
      acc[0][jt] = __builtin_amdgcn_mfma_f32_16x16x32_bf16(ua, wl.s, acc[0][jt], 0, 0, 0);
      acc[1][jt] = __builtin_amdgcn_mfma_f32_16x16x32_bf16(ub, wl.s, acc[1][jt], 0, 0, 0);
    }
  }

#pragma unroll
  for (int mt = 0; mt < 2; ++mt) {
#pragma unroll
    for (int r = 0; r < 4; ++r) {
      int node = n0 + mt * 16 + quad * 4 + r;
      float pc = 0.f, ps = 0.f, pd = 0.f;
#pragma unroll
      for (int jt = 0; jt < 8; ++jt) {
        int jl = w * 128 + jt * 16 + l15;
        float v = acc[mt][jt][r] + sh[jl];
        float e = v > 0.f ? v : expm1f(v);
        pc += e * sh[512 + jl];
        ps += e * sh[1024 + jl];
        pd += e * sh[1536 + jl];
      }
#pragma unroll
      for (int off = 1; off <= 8; off <<= 1) {
        pc += __shfl_xor(pc, off);
        ps += __shfl_xor(ps, off);
        pd += __shfl_xor(pd, off);
      }
      if (l15 == 0 && node < N) {
        atomicAdd(&partc[node], pc);
        atomicAdd(&parts[node], ps);
        atomicAdd(&partd[node], pd);
      }
    }
  }
}

// ---------------- layer-2 attention, all-scalar ----------------

__global__ __launch_bounds__(256) void k_attn2s(const float* __restrict__ partc,
                                                const float* __restrict__ parts,
                                                const float* __restrict__ partd,
                                                const int* __restrict__ row_ptr,
                                                const int* __restrict__ csr,
                                                const float* __restrict__ cconst,
                                                float* __restrict__ out, int N) {
  int w = threadIdx.x >> 6, lane = threadIdx.x & 63;
  int d = blockIdx.x * 4 + w;
  if (d >= N) return;
  int e0 = row_ptr[d], deg = row_ptr[d + 1] - e0;
  float aldd = partd[d];
  float mt = -1e30f, st = 0.f;
  for (int e = lane; e < deg; e += 64) {
    int s = csr[e0 + e];
    float l = leaky(parts[s] + aldd);
    if (l > mt) { st = st * __expf(mt - l) + 1.f; mt = l; }
    else st += __expf(l - mt);
  }
#pragma unroll
  for (int off = 32; off; off >>= 1) {
    float m2 = __shfl_xor(mt, off);
    float s2 = __shfl_xor(st, off);
    float m = fmaxf(mt, m2);
    st = st * __expf(mt - m) + s2 * __expf(m2 - m);
    mt = m;
  }
  float invz = 1.f / (st + 1e-16f);
  float acc = 0.f;
  for (int e = lane; e < deg; e += 64) {
    int s = csr[e0 + e];
    float l = leaky(parts[s] + aldd);
    acc += __expf(l - mt) * partc[s];
  }
#pragma unroll
  for (int off = 32; off; off >>= 1) acc += __shfl_xor(acc, off);
  if (lane == 0) out[d] = acc * invz + cconst[0];
}

// ---------------- launch ----------------

extern "C" void kernel_launch(void* const* d_in, const int* in_sizes, int n_in,
                              void* d_out, int out_size, void* d_ws, size_t ws_size,
                              hipStream_t stream) {
  const float* x      = (const float*)d_in[0];
  const int*   ei     = (const int*)d_in[1];
  const float* W1     = (const float*)d_in[2];
  const float* a_src1 = (const float*)d_in[3];
  const float* a_dst1 = (const float*)d_in[4];
  const float* b1     = (const float*)d_in[5];
  const float* W2     = (const float*)d_in[6];
  const float* a_src2 = (const float*)d_in[7];
  const float* a_dst2 = (const float*)d_in[8];
  const float* b2     = (const float*)d_in[9];
  const float* Wc     = (const float*)d_in[10];
  const float* bc     = (const float*)d_in[11];

  int N = in_sizes[0] / EMBED;
  int E = in_sizes[1] / 2;
  int Et = E + N;
  int nScanB = (N + 255) / 256;

  char* ws = (char*)d_ws;
  size_t off = 0;
  auto alloc = [&](size_t bytes) -> void* {
    void* p = ws + off;
    off += (bytes + 255) & ~(size_t)255;
    return p;
  };
  __hip_bfloat16* xaggb = (__hip_bfloat16*)alloc((size_t)N * 2048 * 2 + 65536);  // +tail slack for staging
  short* w1t_hi = (short*)alloc((size_t)262144 * 2);
  short* w1t_lo = (short*)alloc((size_t)262144 * 2);
  float* wsAll  = (float*)alloc(4096 * 4);
  float* uvec   = (float*)alloc(6144 * 4);
  float* cconst = (float*)alloc(256);
  float* als1   = (float*)alloc((size_t)N * 16 * 4);
  float* ald1   = (float*)alloc((size_t)N * 16 * 4);
  float* iz1    = (float*)alloc((size_t)N * 16 * 4);
  float* part   = (float*)alloc((size_t)3 * N * 4);
  float* partc  = part;
  float* parts  = part + N;
  float* partd  = part + 2 * N;
  int* deg      = (int*)alloc((size_t)N * 4);
  int* excl     = (int*)alloc((size_t)N * 4);
  int* bsum     = (int*)alloc((size_t)(nScanB + 1) * 4);
  int* row_ptr  = (int*)alloc((size_t)(N + 1) * 4);
  int* cursor   = (int*)alloc((size_t)N * 4);
  int* csr      = (int*)alloc((size_t)Et * 4);

  hipMemsetAsync(deg, 0, (size_t)N * 4, stream);
  hipMemsetAsync(part, 0, (size_t)3 * N * 4, stream);

  k_hist<<<(Et + 255) / 256, 256, 0, stream>>>(ei, E, N, deg);
  k_scan1<<<nScanB, 256, 0, stream>>>(deg, excl, bsum, N);
  k_scan2<<<1, 64, 0, stream>>>(bsum, nScanB);
  k_scan3<<<nScanB, 256, 0, stream>>>(deg, excl, bsum, row_ptr, cursor, N);
  k_scatter<<<(Et + 255) / 256, 256, 0, stream>>>(ei, E, N, cursor, csr);

  k_prepAll<<<41, 256, 0, stream>>>(W1, a_src1, a_dst1, W2, a_src2, a_dst2, Wc, b2, bc,
                                    wsAll, uvec, cconst);
  k_prep2aT<<<dim3(16, 2, 2), 256, 0, stream>>>(W1, w1t_hi, w1t_lo);

  k_al1x<<<(N + 3) / 4, 256, 0, stream>>>(x, wsAll, als1, ald1, N);
  k_z<<<(N * 16 + 255) / 256, 256, 0, stream>>>(als1, ald1, row_ptr, csr, iz1, N);
  k_attn1b<<<N, 256, 0, stream>>>(x, als1, ald1, iz1, row_ptr, csr, xaggb, N);

  k_fused<<<dim3((N + 31) / 32, 4), 256, 0, stream>>>(xaggb, w1t_hi, w1t_lo, b1, uvec,
                                                      partc, parts, partd, N);
  k_attn2s<<<(N + 3) / 4, 256, 0, stream>>>(partc, parts, partd, row_ptr, csr, cconst,
                                            (float*)d_out, N);
}

// Round 5
// 251.581 us; speedup vs baseline: 2.4521x; 1.0398x over previous
//
#include <hip/hip_runtime.h>
#include <hip/hip_bf16.h>

#define EMBED 128
#define HEADS 16
#define NEG 0.2f
#define MAXE 256

typedef __attribute__((ext_vector_type(8))) short short8;
typedef __attribute__((ext_vector_type(4))) float floatx4;

static __device__ __forceinline__ float leaky(float x) { return x > 0.f ? x : NEG * x; }

static __device__ __forceinline__ short f2bf_bits(float f) {
  __hip_bfloat16 h = __float2bfloat16(f);
  union { __hip_bfloat16 b; short s; } u;
  u.b = h;
  return u.s;
}

// ---------------- CSR build ----------------

__global__ void k_hist(const int* __restrict__ ei, int E, int N, int* __restrict__ deg) {
  int i = blockIdx.x * blockDim.x + threadIdx.x;
  int Et = E + N;
  if (i >= Et) return;
  int d = (i < E) ? ei[E + i] : (i - E);
  atomicAdd(&deg[d], 1);
}

__global__ __launch_bounds__(256) void k_scan1(const int* __restrict__ deg,
                                               int* __restrict__ excl,
                                               int* __restrict__ bsum, int n) {
  __shared__ int s[256];
  int i = blockIdx.x * 256 + threadIdx.x;
  int v = (i < n) ? deg[i] : 0;
  s[threadIdx.x] = v;
  __syncthreads();
  for (int d = 1; d < 256; d <<= 1) {
    int add = ((int)threadIdx.x >= d) ? s[threadIdx.x - d] : 0;
    __syncthreads();
    s[threadIdx.x] += add;
    __syncthreads();
  }
  if (i < n) excl[i] = s[threadIdx.x] - v;
  if (threadIdx.x == 255) bsum[blockIdx.x] = s[255];
}

__global__ void k_scan2(int* __restrict__ bsum, int nb) {
  if (threadIdx.x == 0 && blockIdx.x == 0) {
    int acc = 0;
    for (int i = 0; i < nb; ++i) { int v = bsum[i]; bsum[i] = acc; acc += v; }
  }
}

__global__ __launch_bounds__(256) void k_scan3(const int* __restrict__ deg,
                                               const int* __restrict__ excl,
                                               const int* __restrict__ bsum,
                                               int* __restrict__ row_ptr,
                                               int* __restrict__ cursor, int n) {
  int i = blockIdx.x * 256 + threadIdx.x;
  if (i < n) {
    int r = excl[i] + bsum[blockIdx.x];
    row_ptr[i] = r;
    cursor[i] = r;
    if (i == n - 1) row_ptr[n] = r + deg[i];
  }
}

__global__ void k_scatter(const int* __restrict__ ei, int E, int N,
                          int* __restrict__ cursor, int* __restrict__ csr_src) {
  int i = blockIdx.x * blockDim.x + threadIdx.x;
  int Et = E + N;
  if (i >= Et) return;
  int s = (i < E) ? ei[i] : (i - E);
  int d = (i < E) ? ei[E + i] : (i - E);
  int pos = atomicAdd(&cursor[d], 1);
  csr_src[pos] = s;
}

// ---------------- merged prep: w~ vectors (layer1 logits) + u vectors (layer2 folded) ----------------

__global__ __launch_bounds__(256) void k_prepAll(const float* __restrict__ W1,
                                                 const float* __restrict__ a_src1,
                                                 const float* __restrict__ a_dst1,
                                                 const float* __restrict__ W2,
                                                 const float* __restrict__ a_src2,
                                                 const float* __restrict__ a_dst2,
                                                 const float* __restrict__ Wc,
                                                 const float* __restrict__ b2,
                                                 const float* __restrict__ bc,
                                                 float* __restrict__ wsAll,
                                                 float* __restrict__ uvec,
                                                 float* __restrict__ cconst) {
  int gid = blockIdx.x * 256 + threadIdx.x;
  if (gid < 4096) {
    int sel = gid >> 11;
    int id = gid & 2047;
    int h = id >> 7, k = id & 127;
    const float* av = sel ? a_dst1 : a_src1;
    float sum = 0.f;
    const float* wrow = W1 + (size_t)k * 2048 + h * 128;
    const float* arow = av + h * 128;
#pragma unroll 4
    for (int c = 0; c < 128; ++c) sum += wrow[c] * arow[c];
    wsAll[gid] = sum;
  } else if (gid < 10240) {
    int g = gid - 4096;
    int sel = g >> 11;  // 0: Wc, 1: a_src2, 2: a_dst2
    int k = g & 2047;
    const float* v = sel == 0 ? Wc : (sel == 1 ? a_src2 : a_dst2);
    const float* wrow = W2 + (size_t)k * 128;
    float s = 0.f;
#pragma unroll 4
    for (int j = 0; j < 128; ++j) s += wrow[j] * v[j];
    uvec[g] = s;
  } else if (gid == 10240) {
    float s = 0.f;
    for (int j = 0; j < 128; ++j) s += b2[j] * Wc[j];
    *cconst = s + bc[0];
  }
}

// ---------------- W1^T hi/lo bf16 via LDS tile transpose: layout [h][j][c] ----------------

__global__ __launch_bounds__(256) void k_prep2aT(const float* __restrict__ W1,
                                                 short* __restrict__ hi,
                                                 short* __restrict__ lo) {
  __shared__ float tile[64][65];
  int h = blockIdx.x;
  int c0 = blockIdx.y * 64;
  int j0 = blockIdx.z * 64;
  int t = threadIdx.x;
#pragma unroll
  for (int i = 0; i < 4; ++i) {
    int idx4 = i * 256 + t;
    int c = idx4 >> 4, j4 = idx4 & 15;
    float4 v = *(const float4*)&W1[(size_t)(c0 + c) * 2048 + h * 128 + j0 + j4 * 4];
    tile[c][j4 * 4 + 0] = v.x;
    tile[c][j4 * 4 + 1] = v.y;
    tile[c][j4 * 4 + 2] = v.z;
    tile[c][j4 * 4 + 3] = v.w;
  }
  __syncthreads();
#pragma unroll
  for (int i = 0; i < 4; ++i) {
    int idx = i * 256 + t;
    int j = idx >> 4, c4 = idx & 15;
    unsigned short vh[4], vl[4];
#pragma unroll
    for (int ii = 0; ii < 4; ++ii) {
      float wv = tile[c4 * 4 + ii][j];
      short hb = f2bf_bits(wv);
      float hf = __uint_as_float(((unsigned int)(unsigned short)hb) << 16);
      vh[ii] = (unsigned short)hb;
      vl[ii] = (unsigned short)f2bf_bits(wv - hf);
    }
    size_t o = (size_t)h * 16384 + (size_t)(j0 + j) * 128 + c0 + c4 * 4;
    *(ushort4*)&hi[o] = make_ushort4(vh[0], vh[1], vh[2], vh[3]);
    *(ushort4*)&lo[o] = make_ushort4(vl[0], vl[1], vl[2], vl[3]);
  }
}

// ---------------- layer-1 logits: thread per (n,h); weights [c][h] in LDS ----------------

__global__ __launch_bounds__(256) void k_al1v2(const float* __restrict__ x,
                                               const float* __restrict__ wsAll,
                                               float* __restrict__ als,
                                               float* __restrict__ ald, int N) {
  __shared__ float wss[128][16], wsd[128][16];
  int tid = threadIdx.x;
  for (int i = tid; i < 2048; i += 256) {
    int h = i >> 7, c = i & 127;
    wss[c][h] = wsAll[i];
    wsd[c][h] = wsAll[2048 + i];
  }
  __syncthreads();
  int gid = blockIdx.x * 256 + tid;
  int n = gid >> 4, h = gid & 15;
  if (n >= N) return;
  const float4* xp = (const float4*)(x + (size_t)n * 128);
  float ps = 0.f, pd = 0.f;
#pragma unroll 8
  for (int c4 = 0; c4 < 32; ++c4) {
    float4 xv = xp[c4];
    int c = c4 * 4;
    ps += xv.x * wss[c][h] + xv.y * wss[c + 1][h] + xv.z * wss[c + 2][h] + xv.w * wss[c + 3][h];
    pd += xv.x * wsd[c][h] + xv.y * wsd[c + 1][h] + xv.z * wsd[c + 2][h] + xv.w * wsd[c + 3][h];
  }
  als[gid] = ps;
  ald[gid] = pd;
}

// ---------------- layer-1 attention in x-space (z fused, exp cached) -> xagg bf16 ----------------

__global__ __launch_bounds__(256) void k_attn1c(const float* __restrict__ x,
                                                const float* __restrict__ als,
                                                const float* __restrict__ ald,
                                                const int* __restrict__ row_ptr,
                                                const int* __restrict__ csr,
                                                __hip_bfloat16* __restrict__ xaggb,
                                                int N) {
  int d = blockIdx.x;
  int tid = threadIdx.x;
  int e0 = row_ptr[d];
  int deg = row_ptr[d + 1] - e0;

  __shared__ int srcb[MAXE];
  __shared__ float ex[MAXE][17];
  __shared__ float xs[16][132];
  __shared__ float red[16][17];
  __shared__ float ald_sh[16], iz_sh[16];

  if (tid < 16) ald_sh[tid] = ald[(size_t)d * 16 + tid];
  __syncthreads();

  int hh = tid & 15, er = tid >> 4;
  float aldh = ald_sh[hh];
  int cg = tid & 15, h2 = tid >> 4;
  float acc[8] = {0.f, 0.f, 0.f, 0.f, 0.f, 0.f, 0.f, 0.f};

  if (deg <= MAXE) {
    // load edge list once
    for (int e = tid; e < deg; e += 256) srcb[e] = csr[e0 + e];
    __syncthreads();
    // pass 1: exp + z
    float zp = 0.f;
    for (int e = er; e < deg; e += 16) {
      float l = leaky(als[(size_t)srcb[e] * 16 + hh] + aldh);
      float v = __expf(l);
      ex[e][hh] = v;
      zp += v;
    }
    red[er][hh] = zp;
    __syncthreads();
    if (tid < 16) {
      float z = 0.f;
#pragma unroll
      for (int k = 0; k < 16; ++k) z += red[k][tid];
      iz_sh[tid] = 1.f / (z + 1e-16f);
    }
    __syncthreads();
    // pre-scale exp by 1/z
    float izh = iz_sh[hh];
    for (int e = er; e < deg; e += 16) ex[e][hh] *= izh;
    __syncthreads();
    // pass 2: gather x, aggregate
    for (int base = 0; base < deg; base += 16) {
      int nb = min(16, deg - base);
      int r = tid >> 4;
      if (r < nb) {
        const float4* xp = (const float4*)(x + (size_t)srcb[base + r] * 128) + (tid & 15) * 2;
        float4 v0 = xp[0], v1 = xp[1];
        *(float4*)&xs[r][(tid & 15) * 8] = v0;
        *(float4*)&xs[r][(tid & 15) * 8 + 4] = v1;
      }
      __syncthreads();
      for (int e = 0; e < nb; ++e) {
        float a = ex[base + e][h2];
        float4 v0 = *(const float4*)&xs[e][cg * 8];
        float4 v1 = *(const float4*)&xs[e][cg * 8 + 4];
        acc[0] += a * v0.x; acc[1] += a * v0.y; acc[2] += a * v0.z; acc[3] += a * v0.w;
        acc[4] += a * v1.x; acc[5] += a * v1.y; acc[6] += a * v1.z; acc[7] += a * v1.w;
      }
      __syncthreads();
    }
  } else {
    // slow path: chunked with recompute (rare)
    float zp = 0.f;
    for (int e = er; e < deg; e += 16) {
      int s = csr[e0 + e];
      zp += __expf(leaky(als[(size_t)s * 16 + hh] + aldh));
    }
    red[er][hh] = zp;
    __syncthreads();
    if (tid < 16) {
      float z = 0.f;
#pragma unroll
      for (int k = 0; k < 16; ++k) z += red[k][tid];
      iz_sh[tid] = 1.f / (z + 1e-16f);
    }
    __syncthreads();
    float izh = iz_sh[hh];
    for (int base = 0; base < deg; base += 16) {
      int nb = min(16, deg - base);
      __syncthreads();
      if (tid < nb) srcb[tid] = csr[e0 + base + tid];
      __syncthreads();
      if (tid < nb * 16) {
        int e = tid >> 4;
        float l = leaky(als[(size_t)srcb[e] * 16 + hh] + aldh);
        ex[e][hh] = __expf(l) * izh;
      }
      {
        int r = tid >> 4;
        if (r < nb) {
          const float4* xp = (const float4*)(x + (size_t)srcb[r] * 128) + (tid & 15) * 2;
          float4 v0 = xp[0], v1 = xp[1];
          *(float4*)&xs[r][(tid & 15) * 8] = v0;
          *(float4*)&xs[r][(tid & 15) * 8 + 4] = v1;
        }
      }
      __syncthreads();
      for (int e = 0; e < nb; ++e) {
        float a = ex[e][h2];
        float4 v0 = *(const float4*)&xs[e][cg * 8];
        float4 v1 = *(const float4*)&xs[e][cg * 8 + 4];
        acc[0] += a * v0.x; acc[1] += a * v0.y; acc[2] += a * v0.z; acc[3] += a * v0.w;
        acc[4] += a * v1.x; acc[5] += a * v1.y; acc[6] += a * v1.z; acc[7] += a * v1.w;
      }
    }
  }

  __hip_bfloat16 tmp[8];
#pragma unroll
  for (int i = 0; i < 8; ++i) tmp[i] = __float2bfloat16(acc[i]);
  *(uint4*)&xaggb[(size_t)d * 2048 + h2 * 128 + cg * 8] = *(uint4*)tmp;
}

// ---------------- fused: ELU(xagg @ bdiag(W1) + b1) contracted with u vectors ----------------
// grid (ceil(N/64), 4). Block stages A (64 nodes x 4 heads = 64KB) in LDS;
// wave w = head by*4+w, 4 m-tiles of 16 nodes; B (W1^T hi/lo bf16) streamed from L2.

__global__ __launch_bounds__(256, 2) void k_fused(const __hip_bfloat16* __restrict__ xaggb,
                                                  const short* __restrict__ w1t_hi,
                                                  const short* __restrict__ w1t_lo,
                                                  const float* __restrict__ b1,
                                                  const float* __restrict__ uvec,
                                                  float* __restrict__ partc,
                                                  float* __restrict__ parts,
                                                  float* __restrict__ partd,
                                                  int N) {
  __shared__ float sh[2048];
  __shared__ __align__(16) char Ash[64 * 1040];
  int tid = threadIdx.x;
  int by = blockIdx.y;
  int base = by * 512;
#pragma unroll
  for (int i = 0; i < 8; ++i) {
    int idx = tid + 256 * i;
    int arr = idx >> 9, off = idx & 511;
    sh[idx] = (arr == 0) ? b1[base + off] : uvec[(arr - 1) * 2048 + base + off];
  }
  int n0 = blockIdx.x * 64;
#pragma unroll
  for (int i = 0; i < 16; ++i) {
    int flat = i * 4096 + tid * 16;  // byte index in unpadded 64KB A block
    int row = flat >> 10;
    int within = flat & 1023;
    int node = n0 + row;
    if (node >= N) node = N - 1;
    uint4 v = *(const uint4*)((const char*)xaggb + (size_t)node * 4096 + by * 1024 + within);
    *(uint4*)(Ash + row * 1040 + within) = v;
  }
  __syncthreads();

  int w = tid >> 6, lane = tid & 63;
  int h = by * 4 + w;
  int quad = lane >> 4, l15 = lane & 15;

  floatx4 acc[4][8];
#pragma unroll
  for (int mt = 0; mt < 4; ++mt)
#pragma unroll
    for (int jt = 0; jt < 8; ++jt) acc[mt][jt] = (floatx4)(0.f);

  const short* bh = w1t_hi + h * 16384;
  const short* bl = w1t_lo + h * 16384;

  for (int ks = 0; ks < 4; ++ks) {
    short8 ua[4];
#pragma unroll
    for (int mt = 0; mt < 4; ++mt)
      ua[mt] = *(const short8*)(Ash + (size_t)(mt * 16 + l15) * 1040 + w * 256 + ks * 64 + quad * 16);
    int koff = ks * 32 + quad * 8;
#pragma unroll
    for (int jt = 0; jt < 8; ++jt) {
      int j = jt * 16 + l15;
      union { uint4 u; short8 s; } wh, wl;
      wh.u = *(const uint4*)(bh + j * 128 + koff);
      wl.u = *(const uint4*)(bl + j * 128 + koff);
#pragma unroll
      for (int mt = 0; mt < 4; ++mt) {
        acc[mt][jt] = __builtin_amdgcn_mfma_f32_16x16x32_bf16(ua[mt], wh.s, acc[mt][jt], 0, 0, 0);
        acc[mt][jt] = __builtin_amdgcn_mfma_f32_16x16x32_bf16(ua[mt], wl.s, acc[mt][jt], 0, 0, 0);
      }
    }
  }

#pragma unroll
  for (int mt = 0; mt < 4; ++mt) {
#pragma unroll
    for (int r = 0; r < 4; ++r) {
      int node = n0 + mt * 16 + quad * 4 + r;
      float pc = 0.f, ps = 0.f, pd = 0.f;
#pragma unroll
      for (int jt = 0; jt < 8; ++jt) {
        int jl = w * 128 + jt * 16 + l15;
        float v = acc[mt][jt][r] + sh[jl];
        float e = v > 0.f ? v : expm1f(v);
        pc += e * sh[512 + jl];
        ps += e * sh[1024 + jl];
        pd += e * sh[1536 + jl];
      }
#pragma unroll
      for (int off = 1; off <= 8; off <<= 1) {
        pc += __shfl_xor(pc, off);
        ps += __shfl_xor(ps, off);
        pd += __shfl_xor(pd, off);
      }
      if (l15 == 0 && node < N) {
        atomicAdd(&partc[node], pc);
        atomicAdd(&parts[node], ps);
        atomicAdd(&partd[node], pd);
      }
    }
  }
}

// ---------------- layer-2 attention, all-scalar, single pass (no max) ----------------

__global__ __launch_bounds__(256) void k_attn2s(const float* __restrict__ partc,
                                                const float* __restrict__ parts,
                                                const float* __restrict__ partd,
                                                const int* __restrict__ row_ptr,
                                                const int* __restrict__ csr,
                                                const float* __restrict__ cconst,
                                                float* __restrict__ out, int N) {
  int w = threadIdx.x >> 6, lane = threadIdx.x & 63;
  int d = blockIdx.x * 4 + w;
  if (d >= N) return;
  int e0 = row_ptr[d], deg = row_ptr[d + 1] - e0;
  float aldd = partd[d];
  float z = 0.f, num = 0.f;
  for (int e = lane; e < deg; e += 64) {
    int s = csr[e0 + e];
    float v = __expf(leaky(parts[s] + aldd));
    z += v;
    num += v * partc[s];
  }
#pragma unroll
  for (int off = 32; off; off >>= 1) {
    z += __shfl_xor(z, off);
    num += __shfl_xor(num, off);
  }
  if (lane == 0) out[d] = num / (z + 1e-16f) + cconst[0];
}

// ---------------- launch ----------------

extern "C" void kernel_launch(void* const* d_in, const int* in_sizes, int n_in,
                              void* d_out, int out_size, void* d_ws, size_t ws_size,
                              hipStream_t stream) {
  const float* x      = (const float*)d_in[0];
  const int*   ei     = (const int*)d_in[1];
  const float* W1     = (const float*)d_in[2];
  const float* a_src1 = (const float*)d_in[3];
  const float* a_dst1 = (const float*)d_in[4];
  const float* b1     = (const float*)d_in[5];
  const float* W2     = (const float*)d_in[6];
  const float* a_src2 = (const float*)d_in[7];
  const float* a_dst2 = (const float*)d_in[8];
  const float* b2     = (const float*)d_in[9];
  const float* Wc     = (const float*)d_in[10];
  const float* bc     = (const float*)d_in[11];

  int N = in_sizes[0] / EMBED;
  int E = in_sizes[1] / 2;
  int Et = E + N;
  int nScanB = (N + 255) / 256;

  char* ws = (char*)d_ws;
  size_t off = 0;
  auto alloc = [&](size_t bytes) -> void* {
    void* p = ws + off;
    off += (bytes + 255) & ~(size_t)255;
    return p;
  };
  __hip_bfloat16* xaggb = (__hip_bfloat16*)alloc((size_t)N * 2048 * 2 + 65536);
  short* w1t_hi = (short*)alloc((size_t)262144 * 2);
  short* w1t_lo = (short*)alloc((size_t)262144 * 2);
  float* wsAll  = (float*)alloc(4096 * 4);
  float* uvec   = (float*)alloc(6144 * 4);
  float* cconst = (float*)alloc(256);
  float* als1   = (float*)alloc((size_t)N * 16 * 4);
  float* ald1   = (float*)alloc((size_t)N * 16 * 4);
  float* part   = (float*)alloc((size_t)3 * N * 4);
  float* partc  = part;
  float* parts  = part + N;
  float* partd  = part + 2 * N;
  int* deg      = (int*)alloc((size_t)N * 4);
  int* excl     = (int*)alloc((size_t)N * 4);
  int* bsum     = (int*)alloc((size_t)(nScanB + 1) * 4);
  int* row_ptr  = (int*)alloc((size_t)(N + 1) * 4);
  int* cursor   = (int*)alloc((size_t)N * 4);
  int* csr      = (int*)alloc((size_t)Et * 4);

  hipMemsetAsync(deg, 0, (size_t)N * 4, stream);
  hipMemsetAsync(part, 0, (size_t)3 * N * 4, stream);

  k_hist<<<(Et + 255) / 256, 256, 0, stream>>>(ei, E, N, deg);
  k_scan1<<<nScanB, 256, 0, stream>>>(deg, excl, bsum, N);
  k_scan2<<<1, 64, 0, stream>>>(bsum, nScanB);
  k_scan3<<<nScanB, 256, 0, stream>>>(deg, excl, bsum, row_ptr, cursor, N);
  k_scatter<<<(Et + 255) / 256, 256, 0, stream>>>(ei, E, N, cursor, csr);

  k_prepAll<<<41, 256, 0, stream>>>(W1, a_src1, a_dst1, W2, a_src2, a_dst2, Wc, b2, bc,
                                    wsAll, uvec, cconst);
  k_prep2aT<<<dim3(16, 2, 2), 256, 0, stream>>>(W1, w1t_hi, w1t_lo);

  k_al1v2<<<(N * 16 + 255) / 256, 256, 0, stream>>>(x, wsAll, als1, ald1, N);
  k_attn1c<<<N, 256, 0, stream>>>(x, als1, ald1, row_ptr, csr, xaggb, N);

  k_fused<<<dim3((N + 63) / 64, 4), 256, 0, stream>>>(xaggb, w1t_hi, w1t_lo, b1, uvec,
                                                      partc, parts, partd, N);
  k_attn2s<<<(N + 3) / 4, 256, 0, stream>>>(partc, parts, partd, row_ptr, csr, cconst,
                                            (float*)d_out, N);
}

// Round 7
// 237.411 us; speedup vs baseline: 2.5985x; 1.0597x over previous
//
#include <hip/hip_runtime.h>
#include <hip/hip_bf16.h>

#define EMBED 128
#define HEADS 16
#define NEG 0.2f
#define MAXE 256

typedef __attribute__((ext_vector_type(8))) short short8;
typedef __attribute__((ext_vector_type(4))) float floatx4;

static __device__ __forceinline__ float leaky(float x) { return x > 0.f ? x : NEG * x; }

static __device__ __forceinline__ short f2bf_bits(float f) {
  __hip_bfloat16 h = __float2bfloat16(f);
  union { __hip_bfloat16 b; short s; } u;
  u.b = h;
  return u.s;
}

// ---------------- CSR build ----------------

__global__ void k_hist(const int* __restrict__ ei, int E, int N, int* __restrict__ deg) {
  int i = blockIdx.x * blockDim.x + threadIdx.x;
  int Et = E + N;
  if (i >= Et) return;
  int d = (i < E) ? ei[E + i] : (i - E);
  atomicAdd(&deg[d], 1);
}

__global__ __launch_bounds__(256) void k_scan1(const int* __restrict__ deg,
                                               int* __restrict__ excl,
                                               int* __restrict__ bsum, int n) {
  __shared__ int s[256];
  int i = blockIdx.x * 256 + threadIdx.x;
  int v = (i < n) ? deg[i] : 0;
  s[threadIdx.x] = v;
  __syncthreads();
  for (int d = 1; d < 256; d <<= 1) {
    int add = ((int)threadIdx.x >= d) ? s[threadIdx.x - d] : 0;
    __syncthreads();
    s[threadIdx.x] += add;
    __syncthreads();
  }
  if (i < n) excl[i] = s[threadIdx.x] - v;
  if (threadIdx.x == 255) bsum[blockIdx.x] = s[255];
}

__global__ void k_scan2(int* __restrict__ bsum, int nb) {
  if (threadIdx.x == 0 && blockIdx.x == 0) {
    int acc = 0;
    for (int i = 0; i < nb; ++i) { int v = bsum[i]; bsum[i] = acc; acc += v; }
  }
}

__global__ __launch_bounds__(256) void k_scan3(const int* __restrict__ deg,
                                               const int* __restrict__ excl,
                                               const int* __restrict__ bsum,
                                               int* __restrict__ row_ptr,
                                               int* __restrict__ cursor, int n) {
  int i = blockIdx.x * 256 + threadIdx.x;
  if (i < n) {
    int r = excl[i] + bsum[blockIdx.x];
    row_ptr[i] = r;
    cursor[i] = r;
    if (i == n - 1) row_ptr[n] = r + deg[i];
  }
}

__global__ void k_scatter(const int* __restrict__ ei, int E, int N,
                          int* __restrict__ cursor, int* __restrict__ csr_src) {
  int i = blockIdx.x * blockDim.x + threadIdx.x;
  int Et = E + N;
  if (i >= Et) return;
  int s = (i < E) ? ei[i] : (i - E);
  int d = (i < E) ? ei[E + i] : (i - E);
  int pos = atomicAdd(&cursor[d], 1);
  csr_src[pos] = s;
}

// ---------------- merged prep: w~ vectors (layer1 logits) + u vectors (layer2 folded) ----------------

__global__ __launch_bounds__(256) void k_prepAll(const float* __restrict__ W1,
                                                 const float* __restrict__ a_src1,
                                                 const float* __restrict__ a_dst1,
                                                 const float* __restrict__ W2,
                                                 const float* __restrict__ a_src2,
                                                 const float* __restrict__ a_dst2,
                                                 const float* __restrict__ Wc,
                                                 const float* __restrict__ b2,
                                                 const float* __restrict__ bc,
                                                 float* __restrict__ wsAll,
                                                 float* __restrict__ uvec,
                                                 float* __restrict__ cconst) {
  int gid = blockIdx.x * 256 + threadIdx.x;
  if (gid < 4096) {
    int sel = gid >> 11;
    int id = gid & 2047;
    int h = id >> 7, k = id & 127;
    const float* av = sel ? a_dst1 : a_src1;
    float sum = 0.f;
    const float* wrow = W1 + (size_t)k * 2048 + h * 128;
    const float* arow = av + h * 128;
#pragma unroll 4
    for (int c = 0; c < 128; ++c) sum += wrow[c] * arow[c];
    wsAll[gid] = sum;
  } else if (gid < 10240) {
    int g = gid - 4096;
    int sel = g >> 11;  // 0: Wc, 1: a_src2, 2: a_dst2
    int k = g & 2047;
    const float* v = sel == 0 ? Wc : (sel == 1 ? a_src2 : a_dst2);
    const float* wrow = W2 + (size_t)k * 128;
    float s = 0.f;
#pragma unroll 4
    for (int j = 0; j < 128; ++j) s += wrow[j] * v[j];
    uvec[g] = s;
  } else if (gid == 10240) {
    float s = 0.f;
    for (int j = 0; j < 128; ++j) s += b2[j] * Wc[j];
    *cconst = s + bc[0];
  }
}

// ---------------- W1^T hi/lo bf16 via LDS tile transpose: layout [h][j][c] ----------------

__global__ __launch_bounds__(256) void k_prep2aT(const float* __restrict__ W1,
                                                 short* __restrict__ hi,
                                                 short* __restrict__ lo) {
  __shared__ float tile[64][65];
  int h = blockIdx.x;
  int c0 = blockIdx.y * 64;
  int j0 = blockIdx.z * 64;
  int t = threadIdx.x;
#pragma unroll
  for (int i = 0; i < 4; ++i) {
    int idx4 = i * 256 + t;
    int c = idx4 >> 4, j4 = idx4 & 15;
    float4 v = *(const float4*)&W1[(size_t)(c0 + c) * 2048 + h * 128 + j0 + j4 * 4];
    tile[c][j4 * 4 + 0] = v.x;
    tile[c][j4 * 4 + 1] = v.y;
    tile[c][j4 * 4 + 2] = v.z;
    tile[c][j4 * 4 + 3] = v.w;
  }
  __syncthreads();
#pragma unroll
  for (int i = 0; i < 4; ++i) {
    int idx = i * 256 + t;
    int j = idx >> 4, c4 = idx & 15;
    unsigned short vh[4], vl[4];
#pragma unroll
    for (int ii = 0; ii < 4; ++ii) {
      float wv = tile[c4 * 4 + ii][j];
      short hb = f2bf_bits(wv);
      float hf = __uint_as_float(((unsigned int)(unsigned short)hb) << 16);
      vh[ii] = (unsigned short)hb;
      vl[ii] = (unsigned short)f2bf_bits(wv - hf);
    }
    size_t o = (size_t)h * 16384 + (size_t)(j0 + j) * 128 + c0 + c4 * 4;
    *(ushort4*)&hi[o] = make_ushort4(vh[0], vh[1], vh[2], vh[3]);
    *(ushort4*)&lo[o] = make_ushort4(vl[0], vl[1], vl[2], vl[3]);
  }
}

// ---------------- layer-1 logits: thread per (n,h); weights [c][h] in LDS ----------------

__global__ __launch_bounds__(256) void k_al1v2(const float* __restrict__ x,
                                               const float* __restrict__ wsAll,
                                               float* __restrict__ als,
                                               float* __restrict__ ald, int N) {
  __shared__ float wss[128][16], wsd[128][16];
  int tid = threadIdx.x;
  for (int i = tid; i < 2048; i += 256) {
    int h = i >> 7, c = i & 127;
    wss[c][h] = wsAll[i];
    wsd[c][h] = wsAll[2048 + i];
  }
  __syncthreads();
  int gid = blockIdx.x * 256 + tid;
  int n = gid >> 4, h = gid & 15;
  if (n >= N) return;
  const float4* xp = (const float4*)(x + (size_t)n * 128);
  float ps = 0.f, pd = 0.f;
#pragma unroll 8
  for (int c4 = 0; c4 < 32; ++c4) {
    float4 xv = xp[c4];
    int c = c4 * 4;
    ps += xv.x * wss[c][h] + xv.y * wss[c + 1][h] + xv.z * wss[c + 2][h] + xv.w * wss[c + 3][h];
    pd += xv.x * wsd[c][h] + xv.y * wsd[c + 1][h] + xv.z * wsd[c + 2][h] + xv.w * wsd[c + 3][h];
  }
  als[gid] = ps;
  ald[gid] = pd;
}

// ---------------- layer-1 attention in x-space (z fused, exp cached) -> xagg bf16 ----------------

__global__ __launch_bounds__(256) void k_attn1c(const float* __restrict__ x,
                                                const float* __restrict__ als,
                                                const float* __restrict__ ald,
                                                const int* __restrict__ row_ptr,
                                                const int* __restrict__ csr,
                                                __hip_bfloat16* __restrict__ xaggb,
                                                int N) {
  int d = blockIdx.x;
  int tid = threadIdx.x;
  int e0 = row_ptr[d];
  int deg = row_ptr[d + 1] - e0;

  __shared__ int srcb[MAXE];
  __shared__ float ex[MAXE][17];
  __shared__ float xs[16][132];
  __shared__ float red[16][17];
  __shared__ float ald_sh[16], iz_sh[16];

  if (tid < 16) ald_sh[tid] = ald[(size_t)d * 16 + tid];
  __syncthreads();

  int hh = tid & 15, er = tid >> 4;
  float aldh = ald_sh[hh];
  int cg = tid & 15, h2 = tid >> 4;
  float acc[8] = {0.f, 0.f, 0.f, 0.f, 0.f, 0.f, 0.f, 0.f};

  if (deg <= MAXE) {
    for (int e = tid; e < deg; e += 256) srcb[e] = csr[e0 + e];
    __syncthreads();
    float zp = 0.f;
    for (int e = er; e < deg; e += 16) {
      float l = leaky(als[(size_t)srcb[e] * 16 + hh] + aldh);
      float v = __expf(l);
      ex[e][hh] = v;
      zp += v;
    }
    red[er][hh] = zp;
    __syncthreads();
    if (tid < 16) {
      float z = 0.f;
#pragma unroll
      for (int k = 0; k < 16; ++k) z += red[k][tid];
      iz_sh[tid] = 1.f / (z + 1e-16f);
    }
    __syncthreads();
    float izh = iz_sh[hh];
    for (int e = er; e < deg; e += 16) ex[e][hh] *= izh;
    __syncthreads();
    for (int base = 0; base < deg; base += 16) {
      int nb = min(16, deg - base);
      int r = tid >> 4;
      if (r < nb) {
        const float4* xp = (const float4*)(x + (size_t)srcb[base + r] * 128) + (tid & 15) * 2;
        float4 v0 = xp[0], v1 = xp[1];
        *(float4*)&xs[r][(tid & 15) * 8] = v0;
        *(float4*)&xs[r][(tid & 15) * 8 + 4] = v1;
      }
      __syncthreads();
      for (int e = 0; e < nb; ++e) {
        float a = ex[base + e][h2];
        float4 v0 = *(const float4*)&xs[e][cg * 8];
        float4 v1 = *(const float4*)&xs[e][cg * 8 + 4];
        acc[0] += a * v0.x; acc[1] += a * v0.y; acc[2] += a * v0.z; acc[3] += a * v0.w;
        acc[4] += a * v1.x; acc[5] += a * v1.y; acc[6] += a * v1.z; acc[7] += a * v1.w;
      }
      __syncthreads();
    }
  } else {
    float zp = 0.f;
    for (int e = er; e < deg; e += 16) {
      int s = csr[e0 + e];
      zp += __expf(leaky(als[(size_t)s * 16 + hh] + aldh));
    }
    red[er][hh] = zp;
    __syncthreads();
    if (tid < 16) {
      float z = 0.f;
#pragma unroll
      for (int k = 0; k < 16; ++k) z += red[k][tid];
      iz_sh[tid] = 1.f / (z + 1e-16f);
    }
    __syncthreads();
    float izh = iz_sh[hh];
    for (int base = 0; base < deg; base += 16) {
      int nb = min(16, deg - base);
      __syncthreads();
      if (tid < nb) srcb[tid] = csr[e0 + base + tid];
      __syncthreads();
      if (tid < nb * 16) {
        int e = tid >> 4;
        float l = leaky(als[(size_t)srcb[e] * 16 + hh] + aldh);
        ex[e][hh] = __expf(l) * izh;
      }
      {
        int r = tid >> 4;
        if (r < nb) {
          const float4* xp = (const float4*)(x + (size_t)srcb[r] * 128) + (tid & 15) * 2;
          float4 v0 = xp[0], v1 = xp[1];
          *(float4*)&xs[r][(tid & 15) * 8] = v0;
          *(float4*)&xs[r][(tid & 15) * 8 + 4] = v1;
        }
      }
      __syncthreads();
      for (int e = 0; e < nb; ++e) {
        float a = ex[e][h2];
        float4 v0 = *(const float4*)&xs[e][cg * 8];
        float4 v1 = *(const float4*)&xs[e][cg * 8 + 4];
        acc[0] += a * v0.x; acc[1] += a * v0.y; acc[2] += a * v0.z; acc[3] += a * v0.w;
        acc[4] += a * v1.x; acc[5] += a * v1.y; acc[6] += a * v1.z; acc[7] += a * v1.w;
      }
    }
  }

  __hip_bfloat16 tmp[8];
#pragma unroll
  for (int i = 0; i < 8; ++i) tmp[i] = __float2bfloat16(acc[i]);
  *(uint4*)&xaggb[(size_t)d * 2048 + h2 * 128 + cg * 8] = *(uint4*)tmp;
}

// ---------------- fused v3: block = (128 nodes, 1 head). A+B both in LDS (XOR-swizzled). ----------------
// grid (ceil(N/128), 16). Inner loop: ds_read + MFMA only, no global loads.
// Wave w handles nodes n0 + w*32 .. +31 (2 m-tiles of 16).

__global__ __launch_bounds__(256) void k_fused(const __hip_bfloat16* __restrict__ xaggb,
                                               const short* __restrict__ w1t_hi,
                                               const short* __restrict__ w1t_lo,
                                               const float* __restrict__ b1,
                                               const float* __restrict__ uvec,
                                               float* __restrict__ partc,
                                               float* __restrict__ parts,
                                               float* __restrict__ partd,
                                               int N) {
  __shared__ float sh[512];                       // b1 | uc | us | ud (head slice)
  __shared__ __align__(16) char Ash[32768];       // 128 nodes x 256B, 16B-chunk XOR swizzle
  __shared__ __align__(16) char Bh[32768];        // 128 j x 256B (hi), swizzled
  __shared__ __align__(16) char Bl[32768];        // (lo)
  int tid = threadIdx.x;
  int h = blockIdx.y;
  int n0 = blockIdx.x * 128;

  // FIX (R6 bug): cover all 512 entries with a 256-thread block.
  for (int i = tid; i < 512; i += 256) {
    int arr = i >> 7, jj = i & 127;
    sh[i] = (arr == 0) ? b1[h * 128 + jj] : uvec[(arr - 1) * 2048 + h * 128 + jj];
  }
  const char* gbh = (const char*)(w1t_hi + (size_t)h * 16384);
  const char* gbl = (const char*)(w1t_lo + (size_t)h * 16384);
#pragma unroll
  for (int i = 0; i < 8; ++i) {
    int ci = i * 256 + tid;          // 0..2047
    int row = ci >> 4, kc = ci & 15;
    int po = row * 256 + ((kc ^ (row & 15)) << 4);
    // A
    int gn = n0 + row; if (gn >= N) gn = N - 1;
    *(uint4*)(Ash + po) = *(const uint4*)((const char*)xaggb + (size_t)gn * 4096 + h * 256 + kc * 16);
    // B hi/lo
    *(uint4*)(Bh + po) = *(const uint4*)(gbh + ci * 16);
    *(uint4*)(Bl + po) = *(const uint4*)(gbl + ci * 16);
  }
  __syncthreads();

  int w = tid >> 6, lane = tid & 63;
  int quad = lane >> 4, l15 = lane & 15;
  int nw = n0 + w * 32;

  floatx4 acc[2][8];
#pragma unroll
  for (int mt = 0; mt < 2; ++mt)
#pragma unroll
    for (int jt = 0; jt < 8; ++jt) acc[mt][jt] = (floatx4)(0.f);

  for (int ks = 0; ks < 4; ++ks) {
    int kq = 4 * ks + quad;
    int xo = ((kq ^ l15) << 4);
    short8 ua0 = *(const short8*)(Ash + (w * 32 + l15) * 256 + xo);
    short8 ua1 = *(const short8*)(Ash + (w * 32 + 16 + l15) * 256 + xo);
#pragma unroll
    for (int jt = 0; jt < 8; ++jt) {
      int po = (jt * 16 + l15) * 256 + xo;
      short8 wh = *(const short8*)(Bh + po);
      short8 wl = *(const short8*)(Bl + po);
      acc[0][jt] = __builtin_amdgcn_mfma_f32_16x16x32_bf16(ua0, wh, acc[0][jt], 0, 0, 0);
      acc[1][jt] = __builtin_amdgcn_mfma_f32_16x16x32_bf16(ua1, wh, acc[1][jt], 0, 0, 0);
      acc[0][jt] = __builtin_amdgcn_mfma_f32_16x16x32_bf16(ua0, wl, acc[0][jt], 0, 0, 0);
      acc[1][jt] = __builtin_amdgcn_mfma_f32_16x16x32_bf16(ua1, wl, acc[1][jt], 0, 0, 0);
    }
  }

#pragma unroll
  for (int mt = 0; mt < 2; ++mt) {
#pragma unroll
    for (int r = 0; r < 4; ++r) {
      int node = nw + mt * 16 + quad * 4 + r;
      float pc = 0.f, ps = 0.f, pd = 0.f;
#pragma unroll
      for (int jt = 0; jt < 8; ++jt) {
        int jl = jt * 16 + l15;
        float v = acc[mt][jt][r] + sh[jl];
        float e = v > 0.f ? v : expm1f(v);
        pc += e * sh[128 + jl];
        ps += e * sh[256 + jl];
        pd += e * sh[384 + jl];
      }
#pragma unroll
      for (int off = 1; off <= 8; off <<= 1) {
        pc += __shfl_xor(pc, off);
        ps += __shfl_xor(ps, off);
        pd += __shfl_xor(pd, off);
      }
      if (l15 == 0 && node < N) {
        atomicAdd(&partc[node], pc);
        atomicAdd(&parts[node], ps);
        atomicAdd(&partd[node], pd);
      }
    }
  }
}

// ---------------- layer-2 attention, all-scalar, single pass (no max) ----------------

__global__ __launch_bounds__(256) void k_attn2s(const float* __restrict__ partc,
                                                const float* __restrict__ parts,
                                                const float* __restrict__ partd,
                                                const int* __restrict__ row_ptr,
                                                const int* __restrict__ csr,
                                                const float* __restrict__ cconst,
                                                float* __restrict__ out, int N) {
  int w = threadIdx.x >> 6, lane = threadIdx.x & 63;
  int d = blockIdx.x * 4 + w;
  if (d >= N) return;
  int e0 = row_ptr[d], deg = row_ptr[d + 1] - e0;
  float aldd = partd[d];
  float z = 0.f, num = 0.f;
  for (int e = lane; e < deg; e += 64) {
    int s = csr[e0 + e];
    float v = __expf(leaky(parts[s] + aldd));
    z += v;
    num += v * partc[s];
  }
#pragma unroll
  for (int off = 32; off; off >>= 1) {
    z += __shfl_xor(z, off);
    num += __shfl_xor(num, off);
  }
  if (lane == 0) out[d] = num / (z + 1e-16f) + cconst[0];
}

// ---------------- launch ----------------

extern "C" void kernel_launch(void* const* d_in, const int* in_sizes, int n_in,
                              void* d_out, int out_size, void* d_ws, size_t ws_size,
                              hipStream_t stream) {
  const float* x      = (const float*)d_in[0];
  const int*   ei     = (const int*)d_in[1];
  const float* W1     = (const float*)d_in[2];
  const float* a_src1 = (const float*)d_in[3];
  const float* a_dst1 = (const float*)d_in[4];
  const float* b1     = (const float*)d_in[5];
  const float* W2     = (const float*)d_in[6];
  const float* a_src2 = (const float*)d_in[7];
  const float* a_dst2 = (const float*)d_in[8];
  const float* b2     = (const float*)d_in[9];
  const float* Wc     = (const float*)d_in[10];
  const float* bc     = (const float*)d_in[11];

  int N = in_sizes[0] / EMBED;
  int E = in_sizes[1] / 2;
  int Et = E + N;
  int nScanB = (N + 255) / 256;

  char* ws = (char*)d_ws;
  size_t off = 0;
  auto alloc = [&](size_t bytes) -> void* {
    void* p = ws + off;
    off += (bytes + 255) & ~(size_t)255;
    return p;
  };
  __hip_bfloat16* xaggb = (__hip_bfloat16*)alloc((size_t)N * 2048 * 2 + 65536);
  short* w1t_hi = (short*)alloc((size_t)262144 * 2);
  short* w1t_lo = (short*)alloc((size_t)262144 * 2);
  float* wsAll  = (float*)alloc(4096 * 4);
  float* uvec   = (float*)alloc(6144 * 4);
  float* cconst = (float*)alloc(256);
  float* als1   = (float*)alloc((size_t)N * 16 * 4);
  float* ald1   = (float*)alloc((size_t)N * 16 * 4);
  float* part   = (float*)alloc((size_t)3 * N * 4);
  float* partc  = part;
  float* parts  = part + N;
  float* partd  = part + 2 * N;
  int* deg      = (int*)alloc((size_t)N * 4);
  int* excl     = (int*)alloc((size_t)N * 4);
  int* bsum     = (int*)alloc((size_t)(nScanB + 1) * 4);
  int* row_ptr  = (int*)alloc((size_t)(N + 1) * 4);
  int* cursor   = (int*)alloc((size_t)N * 4);
  int* csr      = (int*)alloc((size_t)Et * 4);

  hipMemsetAsync(deg, 0, (size_t)N * 4, stream);
  hipMemsetAsync(part, 0, (size_t)3 * N * 4, stream);

  k_hist<<<(Et + 255) / 256, 256, 0, stream>>>(ei, E, N, deg);
  k_scan1<<<nScanB, 256, 0, stream>>>(deg, excl, bsum, N);
  k_scan2<<<1, 64, 0, stream>>>(bsum, nScanB);
  k_scan3<<<nScanB, 256, 0, stream>>>(deg, excl, bsum, row_ptr, cursor, N);
  k_scatter<<<(Et + 255) / 256, 256, 0, stream>>>(ei, E, N, cursor, csr);

  k_prepAll<<<41, 256, 0, stream>>>(W1, a_src1, a_dst1, W2, a_src2, a_dst2, Wc, b2, bc,
                                    wsAll, uvec, cconst);
  k_prep2aT<<<dim3(16, 2, 2), 256, 0, stream>>>(W1, w1t_hi, w1t_lo);

  k_al1v2<<<(N * 16 + 255) / 256, 256, 0, stream>>>(x, wsAll, als1, ald1, N);
  k_attn1c<<<N, 256, 0, stream>>>(x, als1, ald1, row_ptr, csr, xaggb, N);

  k_fused<<<dim3((N + 127) / 128, 16), 256, 0, stream>>>(xaggb, w1t_hi, w1t_lo, b1, uvec,
                                                         partc, parts, partd, N);
  k_attn2s<<<(N + 3) / 4, 256, 0, stream>>>(partc, parts, partd, row_ptr, csr, cconst,
                                            (float*)d_out, N);
}

// Round 8
// 224.756 us; speedup vs baseline: 2.7448x; 1.0563x over previous
//
#include <hip/hip_runtime.h>
#include <hip/hip_bf16.h>

#define EMBED 128
#define HEADS 16
#define NEG 0.2f
#define MAXE 256

typedef __attribute__((ext_vector_type(8))) short short8;
typedef __attribute__((ext_vector_type(4))) float floatx4;

static __device__ __forceinline__ float leaky(float x) { return x > 0.f ? x : NEG * x; }

static __device__ __forceinline__ short f2bf_bits(float f) {
  __hip_bfloat16 h = __float2bfloat16(f);
  union { __hip_bfloat16 b; short s; } u;
  u.b = h;
  return u.s;
}

// ---------------- CSR build ----------------

__global__ void k_hist(const int* __restrict__ ei, int E, int N, int* __restrict__ deg) {
  int i = blockIdx.x * blockDim.x + threadIdx.x;
  int Et = E + N;
  if (i >= Et) return;
  int d = (i < E) ? ei[E + i] : (i - E);
  atomicAdd(&deg[d], 1);
}

__global__ __launch_bounds__(256) void k_scan1(const int* __restrict__ deg,
                                               int* __restrict__ excl,
                                               int* __restrict__ bsum, int n) {
  __shared__ int s[256];
  int i = blockIdx.x * 256 + threadIdx.x;
  int v = (i < n) ? deg[i] : 0;
  s[threadIdx.x] = v;
  __syncthreads();
  for (int d = 1; d < 256; d <<= 1) {
    int add = ((int)threadIdx.x >= d) ? s[threadIdx.x - d] : 0;
    __syncthreads();
    s[threadIdx.x] += add;
    __syncthreads();
  }
  if (i < n) excl[i] = s[threadIdx.x] - v;
  if (threadIdx.x == 255) bsum[blockIdx.x] = s[255];
}

__global__ void k_scan2(int* __restrict__ bsum, int nb) {
  if (threadIdx.x == 0 && blockIdx.x == 0) {
    int acc = 0;
    for (int i = 0; i < nb; ++i) { int v = bsum[i]; bsum[i] = acc; acc += v; }
  }
}

__global__ __launch_bounds__(256) void k_scan3(const int* __restrict__ deg,
                                               const int* __restrict__ excl,
                                               const int* __restrict__ bsum,
                                               int* __restrict__ row_ptr,
                                               int* __restrict__ cursor, int n) {
  int i = blockIdx.x * 256 + threadIdx.x;
  if (i < n) {
    int r = excl[i] + bsum[blockIdx.x];
    row_ptr[i] = r;
    cursor[i] = r;
    if (i == n - 1) row_ptr[n] = r + deg[i];
  }
}

__global__ void k_scatter(const int* __restrict__ ei, int E, int N,
                          int* __restrict__ cursor, int* __restrict__ csr_src) {
  int i = blockIdx.x * blockDim.x + threadIdx.x;
  int Et = E + N;
  if (i >= Et) return;
  int s = (i < E) ? ei[i] : (i - E);
  int d = (i < E) ? ei[E + i] : (i - E);
  int pos = atomicAdd(&cursor[d], 1);
  csr_src[pos] = s;
}

// ---------------- merged prep: w~ vectors (layer1 logits) + u vectors (layer2 folded) ----------------

__global__ __launch_bounds__(256) void k_prepAll(const float* __restrict__ W1,
                                                 const float* __restrict__ a_src1,
                                                 const float* __restrict__ a_dst1,
                                                 const float* __restrict__ W2,
                                                 const float* __restrict__ a_src2,
                                                 const float* __restrict__ a_dst2,
                                                 const float* __restrict__ Wc,
                                                 const float* __restrict__ b2,
                                                 const float* __restrict__ bc,
                                                 float* __restrict__ wsAll,
                                                 float* __restrict__ uvec,
                                                 float* __restrict__ cconst) {
  int gid = blockIdx.x * 256 + threadIdx.x;
  if (gid < 4096) {
    int sel = gid >> 11;
    int id = gid & 2047;
    int h = id >> 7, k = id & 127;
    const float* av = sel ? a_dst1 : a_src1;
    float sum = 0.f;
    const float* wrow = W1 + (size_t)k * 2048 + h * 128;
    const float* arow = av + h * 128;
#pragma unroll 4
    for (int c = 0; c < 128; ++c) sum += wrow[c] * arow[c];
    wsAll[gid] = sum;
  } else if (gid < 10240) {
    int g = gid - 4096;
    int sel = g >> 11;  // 0: Wc, 1: a_src2, 2: a_dst2
    int k = g & 2047;
    const float* v = sel == 0 ? Wc : (sel == 1 ? a_src2 : a_dst2);
    const float* wrow = W2 + (size_t)k * 128;
    float s = 0.f;
#pragma unroll 4
    for (int j = 0; j < 128; ++j) s += wrow[j] * v[j];
    uvec[g] = s;
  } else if (gid == 10240) {
    float s = 0.f;
    for (int j = 0; j < 128; ++j) s += b2[j] * Wc[j];
    *cconst = s + bc[0];
  }
}

// ---------------- W1^T hi/lo bf16 via LDS tile transpose: layout [h][j][c] ----------------

__global__ __launch_bounds__(256) void k_prep2aT(const float* __restrict__ W1,
                                                 short* __restrict__ hi,
                                                 short* __restrict__ lo) {
  __shared__ float tile[64][65];
  int h = blockIdx.x;
  int c0 = blockIdx.y * 64;
  int j0 = blockIdx.z * 64;
  int t = threadIdx.x;
#pragma unroll
  for (int i = 0; i < 4; ++i) {
    int idx4 = i * 256 + t;
    int c = idx4 >> 4, j4 = idx4 & 15;
    float4 v = *(const float4*)&W1[(size_t)(c0 + c) * 2048 + h * 128 + j0 + j4 * 4];
    tile[c][j4 * 4 + 0] = v.x;
    tile[c][j4 * 4 + 1] = v.y;
    tile[c][j4 * 4 + 2] = v.z;
    tile[c][j4 * 4 + 3] = v.w;
  }
  __syncthreads();
#pragma unroll
  for (int i = 0; i < 4; ++i) {
    int idx = i * 256 + t;
    int j = idx >> 4, c4 = idx & 15;
    unsigned short vh[4], vl[4];
#pragma unroll
    for (int ii = 0; ii < 4; ++ii) {
      float wv = tile[c4 * 4 + ii][j];
      short hb = f2bf_bits(wv);
      float hf = __uint_as_float(((unsigned int)(unsigned short)hb) << 16);
      vh[ii] = (unsigned short)hb;
      vl[ii] = (unsigned short)f2bf_bits(wv - hf);
    }
    size_t o = (size_t)h * 16384 + (size_t)(j0 + j) * 128 + c0 + c4 * 4;
    *(ushort4*)&hi[o] = make_ushort4(vh[0], vh[1], vh[2], vh[3]);
    *(ushort4*)&lo[o] = make_ushort4(vl[0], vl[1], vl[2], vl[3]);
  }
}

// ---------------- layer-1 logits: thread per (n,h); weights [c][h] in LDS ----------------

__global__ __launch_bounds__(256) void k_al1v2(const float* __restrict__ x,
                                               const float* __restrict__ wsAll,
                                               float* __restrict__ als,
                                               float* __restrict__ ald, int N) {
  __shared__ float wss[128][16], wsd[128][16];
  int tid = threadIdx.x;
  for (int i = tid; i < 2048; i += 256) {
    int h = i >> 7, c = i & 127;
    wss[c][h] = wsAll[i];
    wsd[c][h] = wsAll[2048 + i];
  }
  __syncthreads();
  int gid = blockIdx.x * 256 + tid;
  int n = gid >> 4, h = gid & 15;
  if (n >= N) return;
  const float4* xp = (const float4*)(x + (size_t)n * 128);
  float ps = 0.f, pd = 0.f;
#pragma unroll 8
  for (int c4 = 0; c4 < 32; ++c4) {
    float4 xv = xp[c4];
    int c = c4 * 4;
    ps += xv.x * wss[c][h] + xv.y * wss[c + 1][h] + xv.z * wss[c + 2][h] + xv.w * wss[c + 3][h];
    pd += xv.x * wsd[c][h] + xv.y * wsd[c + 1][h] + xv.z * wsd[c + 2][h] + xv.w * wsd[c + 3][h];
  }
  als[gid] = ps;
  ald[gid] = pd;
}

// ---------------- layer-1 attention in x-space (z fused, exp cached) -> xagg bf16 ----------------
// xagg layout: HEAD-MAJOR [16][N][128] (contiguous per head for k_fused streaming)

__global__ __launch_bounds__(256) void k_attn1c(const float* __restrict__ x,
                                                const float* __restrict__ als,
                                                const float* __restrict__ ald,
                                                const int* __restrict__ row_ptr,
                                                const int* __restrict__ csr,
                                                __hip_bfloat16* __restrict__ xaggb,
                                                int N) {
  int d = blockIdx.x;
  int tid = threadIdx.x;
  int e0 = row_ptr[d];
  int deg = row_ptr[d + 1] - e0;

  __shared__ int srcb[MAXE];
  __shared__ float ex[MAXE][17];
  __shared__ float xs[16][132];
  __shared__ float red[16][17];
  __shared__ float ald_sh[16], iz_sh[16];

  if (tid < 16) ald_sh[tid] = ald[(size_t)d * 16 + tid];
  __syncthreads();

  int hh = tid & 15, er = tid >> 4;
  float aldh = ald_sh[hh];
  int cg = tid & 15, h2 = tid >> 4;
  float acc[8] = {0.f, 0.f, 0.f, 0.f, 0.f, 0.f, 0.f, 0.f};

  if (deg <= MAXE) {
    for (int e = tid; e < deg; e += 256) srcb[e] = csr[e0 + e];
    __syncthreads();
    float zp = 0.f;
    for (int e = er; e < deg; e += 16) {
      float l = leaky(als[(size_t)srcb[e] * 16 + hh] + aldh);
      float v = __expf(l);
      ex[e][hh] = v;
      zp += v;
    }
    red[er][hh] = zp;
    __syncthreads();
    if (tid < 16) {
      float z = 0.f;
#pragma unroll
      for (int k = 0; k < 16; ++k) z += red[k][tid];
      iz_sh[tid] = 1.f / (z + 1e-16f);
    }
    __syncthreads();
    float izh = iz_sh[hh];
    for (int e = er; e < deg; e += 16) ex[e][hh] *= izh;
    __syncthreads();
    for (int base = 0; base < deg; base += 16) {
      int nb = min(16, deg - base);
      int r = tid >> 4;
      if (r < nb) {
        const float4* xp = (const float4*)(x + (size_t)srcb[base + r] * 128) + (tid & 15) * 2;
        float4 v0 = xp[0], v1 = xp[1];
        *(float4*)&xs[r][(tid & 15) * 8] = v0;
        *(float4*)&xs[r][(tid & 15) * 8 + 4] = v1;
      }
      __syncthreads();
      for (int e = 0; e < nb; ++e) {
        float a = ex[base + e][h2];
        float4 v0 = *(const float4*)&xs[e][cg * 8];
        float4 v1 = *(const float4*)&xs[e][cg * 8 + 4];
        acc[0] += a * v0.x; acc[1] += a * v0.y; acc[2] += a * v0.z; acc[3] += a * v0.w;
        acc[4] += a * v1.x; acc[5] += a * v1.y; acc[6] += a * v1.z; acc[7] += a * v1.w;
      }
      __syncthreads();
    }
  } else {
    float zp = 0.f;
    for (int e = er; e < deg; e += 16) {
      int s = csr[e0 + e];
      zp += __expf(leaky(als[(size_t)s * 16 + hh] + aldh));
    }
    red[er][hh] = zp;
    __syncthreads();
    if (tid < 16) {
      float z = 0.f;
#pragma unroll
      for (int k = 0; k < 16; ++k) z += red[k][tid];
      iz_sh[tid] = 1.f / (z + 1e-16f);
    }
    __syncthreads();
    float izh = iz_sh[hh];
    for (int base = 0; base < deg; base += 16) {
      int nb = min(16, deg - base);
      __syncthreads();
      if (tid < nb) srcb[tid] = csr[e0 + base + tid];
      __syncthreads();
      if (tid < nb * 16) {
        int e = tid >> 4;
        float l = leaky(als[(size_t)srcb[e] * 16 + hh] + aldh);
        ex[e][hh] = __expf(l) * izh;
      }
      {
        int r = tid >> 4;
        if (r < nb) {
          const float4* xp = (const float4*)(x + (size_t)srcb[r] * 128) + (tid & 15) * 2;
          float4 v0 = xp[0], v1 = xp[1];
          *(float4*)&xs[r][(tid & 15) * 8] = v0;
          *(float4*)&xs[r][(tid & 15) * 8 + 4] = v1;
        }
      }
      __syncthreads();
      for (int e = 0; e < nb; ++e) {
        float a = ex[e][h2];
        float4 v0 = *(const float4*)&xs[e][cg * 8];
        float4 v1 = *(const float4*)&xs[e][cg * 8 + 4];
        acc[0] += a * v0.x; acc[1] += a * v0.y; acc[2] += a * v0.z; acc[3] += a * v0.w;
        acc[4] += a * v1.x; acc[5] += a * v1.y; acc[6] += a * v1.z; acc[7] += a * v1.w;
      }
    }
  }

  __hip_bfloat16 tmp[8];
#pragma unroll
  for (int i = 0; i < 8; ++i) tmp[i] = __float2bfloat16(acc[i]);
  *(uint4*)&xaggb[(size_t)h2 * N * 128 + (size_t)d * 128 + cg * 8] = *(uint4*)tmp;
}

// ---------------- fused v4: block = (256 nodes, 1 head). B in LDS (swizzled), A in VGPRs. ----------------
// grid (ceil(N/256), 16), 256 thr = 4 waves; wave w = nodes n0+w*64..+63 (4 m-tiles of 16).
// b1 folded into MFMA C-init; u vectors hoisted to registers.

__global__ __launch_bounds__(256, 2) void k_fused(const __hip_bfloat16* __restrict__ xaggb,
                                                  const short* __restrict__ w1t_hi,
                                                  const short* __restrict__ w1t_lo,
                                                  const float* __restrict__ b1,
                                                  const float* __restrict__ uvec,
                                                  float* __restrict__ partc,
                                                  float* __restrict__ parts,
                                                  float* __restrict__ partd,
                                                  int N) {
  __shared__ float sh[512];                       // b1 | uc | us | ud (head slice)
  __shared__ __align__(16) char Bh[32768];        // 128 j x 256B (hi), 16B-chunk XOR swizzle
  __shared__ __align__(16) char Bl[32768];        // (lo)
  int tid = threadIdx.x;
  int h = blockIdx.y;
  int n0 = blockIdx.x * 256;

  for (int i = tid; i < 512; i += 256) {
    int arr = i >> 7, jj = i & 127;
    sh[i] = (arr == 0) ? b1[h * 128 + jj] : uvec[(arr - 1) * 2048 + h * 128 + jj];
  }
  const char* gbh = (const char*)(w1t_hi + (size_t)h * 16384);
  const char* gbl = (const char*)(w1t_lo + (size_t)h * 16384);
#pragma unroll
  for (int i = 0; i < 8; ++i) {
    int ci = i * 256 + tid;          // 0..2047
    int row = ci >> 4, kc = ci & 15;
    int po = row * 256 + ((kc ^ (row & 15)) << 4);
    *(uint4*)(Bh + po) = *(const uint4*)(gbh + ci * 16);
    *(uint4*)(Bl + po) = *(const uint4*)(gbl + ci * 16);
  }

  int w = tid >> 6, lane = tid & 63;
  int quad = lane >> 4, l15 = lane & 15;
  int nw = n0 + w * 64;

  // A fragments: a[mt][ks], node = nw + mt*16 + l15, k = ks*32 + quad*8 .. +7
  const char* abase = (const char*)xaggb + (size_t)h * N * 256;
  short8 a[4][4];
#pragma unroll
  for (int mt = 0; mt < 4; ++mt) {
    int node = nw + mt * 16 + l15;
    if (node >= N) node = N - 1;
    const char* rowp = abase + (size_t)node * 256 + quad * 16;
#pragma unroll
    for (int ks = 0; ks < 4; ++ks)
      a[mt][ks] = *(const short8*)(rowp + ks * 64);
  }
  __syncthreads();

  // u vectors into registers; bias into acc C-init
  float ucr[8], usr[8], udr[8];
  floatx4 acc[4][8];
#pragma unroll
  for (int jt = 0; jt < 8; ++jt) {
    int jl = jt * 16 + l15;
    float b = sh[jl];
    ucr[jt] = sh[128 + jl];
    usr[jt] = sh[256 + jl];
    udr[jt] = sh[384 + jl];
#pragma unroll
    for (int mt = 0; mt < 4; ++mt) acc[mt][jt] = (floatx4)(b);
  }

  for (int ks = 0; ks < 4; ++ks) {
    int xo = (((ks * 4 + quad) ^ l15) << 4);
#pragma unroll
    for (int jt = 0; jt < 8; ++jt) {
      int po = (jt * 16 + l15) * 256 + xo;
      short8 wh = *(const short8*)(Bh + po);
      short8 wl = *(const short8*)(Bl + po);
#pragma unroll
      for (int mt = 0; mt < 4; ++mt) {
        acc[mt][jt] = __builtin_amdgcn_mfma_f32_16x16x32_bf16(a[mt][ks], wh, acc[mt][jt], 0, 0, 0);
        acc[mt][jt] = __builtin_amdgcn_mfma_f32_16x16x32_bf16(a[mt][ks], wl, acc[mt][jt], 0, 0, 0);
      }
    }
  }

#pragma unroll
  for (int mt = 0; mt < 4; ++mt) {
#pragma unroll
    for (int r = 0; r < 4; ++r) {
      int node = nw + mt * 16 + quad * 4 + r;
      float pc = 0.f, ps = 0.f, pd = 0.f;
#pragma unroll
      for (int jt = 0; jt < 8; ++jt) {
        float v = acc[mt][jt][r];
        float e = v > 0.f ? v : expm1f(v);
        pc += e * ucr[jt];
        ps += e * usr[jt];
        pd += e * udr[jt];
      }
#pragma unroll
      for (int off = 1; off <= 8; off <<= 1) {
        pc += __shfl_xor(pc, off);
        ps += __shfl_xor(ps, off);
        pd += __shfl_xor(pd, off);
      }
      if (l15 == 0 && node < N) {
        atomicAdd(&partc[node], pc);
        atomicAdd(&parts[node], ps);
        atomicAdd(&partd[node], pd);
      }
    }
  }
}

// ---------------- layer-2 attention, all-scalar, single pass (no max) ----------------

__global__ __launch_bounds__(256) void k_attn2s(const float* __restrict__ partc,
                                                const float* __restrict__ parts,
                                                const float* __restrict__ partd,
                                                const int* __restrict__ row_ptr,
                                                const int* __restrict__ csr,
                                                const float* __restrict__ cconst,
                                                float* __restrict__ out, int N) {
  int w = threadIdx.x >> 6, lane = threadIdx.x & 63;
  int d = blockIdx.x * 4 + w;
  if (d >= N) return;
  int e0 = row_ptr[d], deg = row_ptr[d + 1] - e0;
  float aldd = partd[d];
  float z = 0.f, num = 0.f;
  for (int e = lane; e < deg; e += 64) {
    int s = csr[e0 + e];
    float v = __expf(leaky(parts[s] + aldd));
    z += v;
    num += v * partc[s];
  }
#pragma unroll
  for (int off = 32; off; off >>= 1) {
    z += __shfl_xor(z, off);
    num += __shfl_xor(num, off);
  }
  if (lane == 0) out[d] = num / (z + 1e-16f) + cconst[0];
}

// ---------------- launch ----------------

extern "C" void kernel_launch(void* const* d_in, const int* in_sizes, int n_in,
                              void* d_out, int out_size, void* d_ws, size_t ws_size,
                              hipStream_t stream) {
  const float* x      = (const float*)d_in[0];
  const int*   ei     = (const int*)d_in[1];
  const float* W1     = (const float*)d_in[2];
  const float* a_src1 = (const float*)d_in[3];
  const float* a_dst1 = (const float*)d_in[4];
  const float* b1     = (const float*)d_in[5];
  const float* W2     = (const float*)d_in[6];
  const float* a_src2 = (const float*)d_in[7];
  const float* a_dst2 = (const float*)d_in[8];
  const float* b2     = (const float*)d_in[9];
  const float* Wc     = (const float*)d_in[10];
  const float* bc     = (const float*)d_in[11];

  int N = in_sizes[0] / EMBED;
  int E = in_sizes[1] / 2;
  int Et = E + N;
  int nScanB = (N + 255) / 256;

  char* ws = (char*)d_ws;
  size_t off = 0;
  auto alloc = [&](size_t bytes) -> void* {
    void* p = ws + off;
    off += (bytes + 255) & ~(size_t)255;
    return p;
  };
  __hip_bfloat16* xaggb = (__hip_bfloat16*)alloc((size_t)N * 2048 * 2 + 65536);
  short* w1t_hi = (short*)alloc((size_t)262144 * 2);
  short* w1t_lo = (short*)alloc((size_t)262144 * 2);
  float* wsAll  = (float*)alloc(4096 * 4);
  float* uvec   = (float*)alloc(6144 * 4);
  float* cconst = (float*)alloc(256);
  float* als1   = (float*)alloc((size_t)N * 16 * 4);
  float* ald1   = (float*)alloc((size_t)N * 16 * 4);
  float* part   = (float*)alloc((size_t)3 * N * 4);
  float* partc  = part;
  float* parts  = part + N;
  float* partd  = part + 2 * N;
  int* deg      = (int*)alloc((size_t)N * 4);
  int* excl     = (int*)alloc((size_t)N * 4);
  int* bsum     = (int*)alloc((size_t)(nScanB + 1) * 4);
  int* row_ptr  = (int*)alloc((size_t)(N + 1) * 4);
  int* cursor   = (int*)alloc((size_t)N * 4);
  int* csr      = (int*)alloc((size_t)Et * 4);

  hipMemsetAsync(deg, 0, (size_t)N * 4, stream);
  hipMemsetAsync(part, 0, (size_t)3 * N * 4, stream);

  k_hist<<<(Et + 255) / 256, 256, 0, stream>>>(ei, E, N, deg);
  k_scan1<<<nScanB, 256, 0, stream>>>(deg, excl, bsum, N);
  k_scan2<<<1, 64, 0, stream>>>(bsum, nScanB);
  k_scan3<<<nScanB, 256, 0, stream>>>(deg, excl, bsum, row_ptr, cursor, N);
  k_scatter<<<(Et + 255) / 256, 256, 0, stream>>>(ei, E, N, cursor, csr);

  k_prepAll<<<41, 256, 0, stream>>>(W1, a_src1, a_dst1, W2, a_src2, a_dst2, Wc, b2, bc,
                                    wsAll, uvec, cconst);
  k_prep2aT<<<dim3(16, 2, 2), 256, 0, stream>>>(W1, w1t_hi, w1t_lo);

  k_al1v2<<<(N * 16 + 255) / 256, 256, 0, stream>>>(x, wsAll, als1, ald1, N);
  k_attn1c<<<N, 256, 0, stream>>>(x, als1, ald1, row_ptr, csr, xaggb, N);

  k_fused<<<dim3((N + 255) / 256, 16), 256, 0, stream>>>(xaggb, w1t_hi, w1t_lo, b1, uvec,
                                                         partc, parts, partd, N);
  k_attn2s<<<(N + 3) / 4, 256, 0, stream>>>(partc, parts, partd, row_ptr, csr, cconst,
                                            (float*)d_out, N);
}

// Round 9
// 216.253 us; speedup vs baseline: 2.8527x; 1.0393x over previous
//
#include <hip/hip_runtime.h>
#include <hip/hip_bf16.h>

#define EMBED 128
#define HEADS 16
#define NEG 0.2f
#define MAXE 256

typedef __attribute__((ext_vector_type(8))) short short8;
typedef __attribute__((ext_vector_type(4))) float floatx4;

static __device__ __forceinline__ float leaky(float x) { return x > 0.f ? x : NEG * x; }

static __device__ __forceinline__ short f2bf_bits(float f) {
  __hip_bfloat16 h = __float2bfloat16(f);
  union { __hip_bfloat16 b; short s; } u;
  u.b = h;
  return u.s;
}

// ---------------- CSR build ----------------

__global__ void k_hist(const int* __restrict__ ei, int E, int N, int* __restrict__ deg) {
  int i = blockIdx.x * blockDim.x + threadIdx.x;
  int Et = E + N;
  if (i >= Et) return;
  int d = (i < E) ? ei[E + i] : (i - E);
  atomicAdd(&deg[d], 1);
}

__global__ __launch_bounds__(256) void k_scan1(const int* __restrict__ deg,
                                               int* __restrict__ excl,
                                               int* __restrict__ bsum, int n) {
  __shared__ int s[256];
  int i = blockIdx.x * 256 + threadIdx.x;
  int v = (i < n) ? deg[i] : 0;
  s[threadIdx.x] = v;
  __syncthreads();
  for (int d = 1; d < 256; d <<= 1) {
    int add = ((int)threadIdx.x >= d) ? s[threadIdx.x - d] : 0;
    __syncthreads();
    s[threadIdx.x] += add;
    __syncthreads();
  }
  if (i < n) excl[i] = s[threadIdx.x] - v;
  if (threadIdx.x == 255) bsum[blockIdx.x] = s[255];
}

__global__ void k_scan2(int* __restrict__ bsum, int nb) {
  if (threadIdx.x == 0 && blockIdx.x == 0) {
    int acc = 0;
    for (int i = 0; i < nb; ++i) { int v = bsum[i]; bsum[i] = acc; acc += v; }
  }
}

__global__ __launch_bounds__(256) void k_scan3(const int* __restrict__ deg,
                                               const int* __restrict__ excl,
                                               const int* __restrict__ bsum,
                                               int* __restrict__ row_ptr,
                                               int* __restrict__ cursor, int n) {
  int i = blockIdx.x * 256 + threadIdx.x;
  if (i < n) {
    int r = excl[i] + bsum[blockIdx.x];
    row_ptr[i] = r;
    cursor[i] = r;
    if (i == n - 1) row_ptr[n] = r + deg[i];
  }
}

__global__ void k_scatter(const int* __restrict__ ei, int E, int N,
                          int* __restrict__ cursor, int* __restrict__ csr_src) {
  int i = blockIdx.x * blockDim.x + threadIdx.x;
  int Et = E + N;
  if (i >= Et) return;
  int s = (i < E) ? ei[i] : (i - E);
  int d = (i < E) ? ei[E + i] : (i - E);
  int pos = atomicAdd(&cursor[d], 1);
  csr_src[pos] = s;
}

// ---------------- merged prep: w~ vectors (layer1 logits) + u vectors (layer2 folded) ----------------

__global__ __launch_bounds__(256) void k_prepAll(const float* __restrict__ W1,
                                                 const float* __restrict__ a_src1,
                                                 const float* __restrict__ a_dst1,
                                                 const float* __restrict__ W2,
                                                 const float* __restrict__ a_src2,
                                                 const float* __restrict__ a_dst2,
                                                 const float* __restrict__ Wc,
                                                 const float* __restrict__ b2,
                                                 const float* __restrict__ bc,
                                                 float* __restrict__ wsAll,
                                                 float* __restrict__ uvec,
                                                 float* __restrict__ cconst) {
  int gid = blockIdx.x * 256 + threadIdx.x;
  if (gid < 4096) {
    int sel = gid >> 11;
    int id = gid & 2047;
    int h = id >> 7, k = id & 127;
    const float* av = sel ? a_dst1 : a_src1;
    float sum = 0.f;
    const float* wrow = W1 + (size_t)k * 2048 + h * 128;
    const float* arow = av + h * 128;
#pragma unroll 4
    for (int c = 0; c < 128; ++c) sum += wrow[c] * arow[c];
    wsAll[gid] = sum;
  } else if (gid < 10240) {
    int g = gid - 4096;
    int sel = g >> 11;  // 0: Wc, 1: a_src2, 2: a_dst2
    int k = g & 2047;
    const float* v = sel == 0 ? Wc : (sel == 1 ? a_src2 : a_dst2);
    const float* wrow = W2 + (size_t)k * 128;
    float s = 0.f;
#pragma unroll 4
    for (int j = 0; j < 128; ++j) s += wrow[j] * v[j];
    uvec[g] = s;
  } else if (gid == 10240) {
    float s = 0.f;
    for (int j = 0; j < 128; ++j) s += b2[j] * Wc[j];
    *cconst = s + bc[0];
  }
}

// ---------------- W1^T hi/lo bf16 via LDS tile transpose: layout [h][j][c] ----------------

__global__ __launch_bounds__(256) void k_prep2aT(const float* __restrict__ W1,
                                                 short* __restrict__ hi,
                                                 short* __restrict__ lo) {
  __shared__ float tile[64][65];
  int h = blockIdx.x;
  int c0 = blockIdx.y * 64;
  int j0 = blockIdx.z * 64;
  int t = threadIdx.x;
#pragma unroll
  for (int i = 0; i < 4; ++i) {
    int idx4 = i * 256 + t;
    int c = idx4 >> 4, j4 = idx4 & 15;
    float4 v = *(const float4*)&W1[(size_t)(c0 + c) * 2048 + h * 128 + j0 + j4 * 4];
    tile[c][j4 * 4 + 0] = v.x;
    tile[c][j4 * 4 + 1] = v.y;
    tile[c][j4 * 4 + 2] = v.z;
    tile[c][j4 * 4 + 3] = v.w;
  }
  __syncthreads();
#pragma unroll
  for (int i = 0; i < 4; ++i) {
    int idx = i * 256 + t;
    int j = idx >> 4, c4 = idx & 15;
    unsigned short vh[4], vl[4];
#pragma unroll
    for (int ii = 0; ii < 4; ++ii) {
      float wv = tile[c4 * 4 + ii][j];
      short hb = f2bf_bits(wv);
      float hf = __uint_as_float(((unsigned int)(unsigned short)hb) << 16);
      vh[ii] = (unsigned short)hb;
      vl[ii] = (unsigned short)f2bf_bits(wv - hf);
    }
    size_t o = (size_t)h * 16384 + (size_t)(j0 + j) * 128 + c0 + c4 * 4;
    *(ushort4*)&hi[o] = make_ushort4(vh[0], vh[1], vh[2], vh[3]);
    *(ushort4*)&lo[o] = make_ushort4(vl[0], vl[1], vl[2], vl[3]);
  }
}

// ---------------- layer-1 logits: thread per (n,h); weights [c][h] in LDS ----------------

__global__ __launch_bounds__(256) void k_al1v2(const float* __restrict__ x,
                                               const float* __restrict__ wsAll,
                                               float* __restrict__ als,
                                               float* __restrict__ ald, int N) {
  __shared__ float wss[128][16], wsd[128][16];
  int tid = threadIdx.x;
  for (int i = tid; i < 2048; i += 256) {
    int h = i >> 7, c = i & 127;
    wss[c][h] = wsAll[i];
    wsd[c][h] = wsAll[2048 + i];
  }
  __syncthreads();
  int gid = blockIdx.x * 256 + tid;
  int n = gid >> 4, h = gid & 15;
  if (n >= N) return;
  const float4* xp = (const float4*)(x + (size_t)n * 128);
  float ps = 0.f, pd = 0.f;
#pragma unroll 8
  for (int c4 = 0; c4 < 32; ++c4) {
    float4 xv = xp[c4];
    int c = c4 * 4;
    ps += xv.x * wss[c][h] + xv.y * wss[c + 1][h] + xv.z * wss[c + 2][h] + xv.w * wss[c + 3][h];
    pd += xv.x * wsd[c][h] + xv.y * wsd[c + 1][h] + xv.z * wsd[c + 2][h] + xv.w * wsd[c + 3][h];
  }
  als[gid] = ps;
  ald[gid] = pd;
}

// ---------------- layer-1 attention in x-space, v2 ----------------
// Conflict-fixed (channel-strided ownership: 2-way bank aliasing = free) and
// late-normalized (acc *= 1/z at end; no rescale pass; 2 syncs/chunk).
// xagg layout: HEAD-MAJOR [16][N][128].

__global__ __launch_bounds__(256) void k_attn1d(const float* __restrict__ x,
                                                const float* __restrict__ als,
                                                const float* __restrict__ ald,
                                                const int* __restrict__ row_ptr,
                                                const int* __restrict__ csr,
                                                __hip_bfloat16* __restrict__ xaggb,
                                                int N) {
  int d = blockIdx.x;
  int tid = threadIdx.x;
  int e0 = row_ptr[d];
  int deg = row_ptr[d + 1] - e0;

  __shared__ int srcb[MAXE];
  __shared__ float ex[MAXE][17];
  __shared__ float xs[16][132];
  __shared__ float red[16][17];
  __shared__ float ald_sh[16], iz_sh[16];

  if (tid < 16) ald_sh[tid] = ald[(size_t)d * 16 + tid];
  __syncthreads();

  int hh = tid & 15, er = tid >> 4;
  float aldh = ald_sh[hh];
  int cg = tid & 15, h2 = tid >> 4;   // thread owns head h2, channels [cg*4,+4) and [64+cg*4,+4)
  float acc[8] = {0.f, 0.f, 0.f, 0.f, 0.f, 0.f, 0.f, 0.f};

  if (deg <= MAXE) {
    for (int e = tid; e < deg; e += 256) srcb[e] = csr[e0 + e];
    __syncthreads();
    // phase 1: raw exp + z partials
    float zp = 0.f;
    for (int e = er; e < deg; e += 16) {
      float v = __expf(leaky(als[(size_t)srcb[e] * 16 + hh] + aldh));
      ex[e][hh] = v;
      zp += v;
    }
    red[er][hh] = zp;
    __syncthreads();
    if (tid < 16) {
      float z = 0.f;
#pragma unroll
      for (int k = 0; k < 16; ++k) z += red[k][tid];
      iz_sh[tid] = 1.f / (z + 1e-16f);
    }
    // phase 2: gather x, aggregate with raw exp weights (iz applied at end)
    for (int base = 0; base < deg; base += 16) {
      int nb = min(16, deg - base);
      if (er < nb) {
        const float* xr = x + (size_t)srcb[base + er] * 128;
        *(float4*)&xs[er][cg * 4]      = *(const float4*)&xr[cg * 4];
        *(float4*)&xs[er][64 + cg * 4] = *(const float4*)&xr[64 + cg * 4];
      }
      __syncthreads();
      for (int e = 0; e < nb; ++e) {
        float a = ex[base + e][h2];
        float4 v0 = *(const float4*)&xs[e][cg * 4];
        float4 v1 = *(const float4*)&xs[e][64 + cg * 4];
        acc[0] += a * v0.x; acc[1] += a * v0.y; acc[2] += a * v0.z; acc[3] += a * v0.w;
        acc[4] += a * v1.x; acc[5] += a * v1.y; acc[6] += a * v1.z; acc[7] += a * v1.w;
      }
      __syncthreads();
    }
  } else {
    // slow path: chunked with recompute (rare)
    float zp = 0.f;
    for (int e = er; e < deg; e += 16) {
      int s = csr[e0 + e];
      zp += __expf(leaky(als[(size_t)s * 16 + hh] + aldh));
    }
    red[er][hh] = zp;
    __syncthreads();
    if (tid < 16) {
      float z = 0.f;
#pragma unroll
      for (int k = 0; k < 16; ++k) z += red[k][tid];
      iz_sh[tid] = 1.f / (z + 1e-16f);
    }
    for (int base = 0; base < deg; base += 16) {
      int nb = min(16, deg - base);
      __syncthreads();
      if (tid < nb) srcb[tid] = csr[e0 + base + tid];
      __syncthreads();
      if (tid < nb * 16) {
        int e = tid >> 4;
        ex[e][hh] = __expf(leaky(als[(size_t)srcb[e] * 16 + hh] + aldh));
      }
      if (er < nb) {
        const float* xr = x + (size_t)srcb[er] * 128;
        *(float4*)&xs[er][cg * 4]      = *(const float4*)&xr[cg * 4];
        *(float4*)&xs[er][64 + cg * 4] = *(const float4*)&xr[64 + cg * 4];
      }
      __syncthreads();
      for (int e = 0; e < nb; ++e) {
        float a = ex[e][h2];
        float4 v0 = *(const float4*)&xs[e][cg * 4];
        float4 v1 = *(const float4*)&xs[e][64 + cg * 4];
        acc[0] += a * v0.x; acc[1] += a * v0.y; acc[2] += a * v0.z; acc[3] += a * v0.w;
        acc[4] += a * v1.x; acc[5] += a * v1.y; acc[6] += a * v1.z; acc[7] += a * v1.w;
      }
    }
    __syncthreads();
  }

  float izh = iz_sh[h2];
  __hip_bfloat16 t0[4], t1[4];
#pragma unroll
  for (int i = 0; i < 4; ++i) {
    t0[i] = __float2bfloat16(acc[i] * izh);
    t1[i] = __float2bfloat16(acc[4 + i] * izh);
  }
  __hip_bfloat16* op = xaggb + (size_t)h2 * N * 128 + (size_t)d * 128;
  *(uint2*)&op[cg * 4]      = *(uint2*)t0;
  *(uint2*)&op[64 + cg * 4] = *(uint2*)t1;
}

// ---------------- fused v4: block = (256 nodes, 1 head). B in LDS (swizzled), A in VGPRs. ----------------

__global__ __launch_bounds__(256, 2) void k_fused(const __hip_bfloat16* __restrict__ xaggb,
                                                  const short* __restrict__ w1t_hi,
                                                  const short* __restrict__ w1t_lo,
                                                  const float* __restrict__ b1,
                                                  const float* __restrict__ uvec,
                                                  float* __restrict__ partc,
                                                  float* __restrict__ parts,
                                                  float* __restrict__ partd,
                                                  int N) {
  __shared__ float sh[512];                       // b1 | uc | us | ud (head slice)
  __shared__ __align__(16) char Bh[32768];        // 128 j x 256B (hi), 16B-chunk XOR swizzle
  __shared__ __align__(16) char Bl[32768];        // (lo)
  int tid = threadIdx.x;
  int h = blockIdx.y;
  int n0 = blockIdx.x * 256;

  for (int i = tid; i < 512; i += 256) {
    int arr = i >> 7, jj = i & 127;
    sh[i] = (arr == 0) ? b1[h * 128 + jj] : uvec[(arr - 1) * 2048 + h * 128 + jj];
  }
  const char* gbh = (const char*)(w1t_hi + (size_t)h * 16384);
  const char* gbl = (const char*)(w1t_lo + (size_t)h * 16384);
#pragma unroll
  for (int i = 0; i < 8; ++i) {
    int ci = i * 256 + tid;          // 0..2047
    int row = ci >> 4, kc = ci & 15;
    int po = row * 256 + ((kc ^ (row & 15)) << 4);
    *(uint4*)(Bh + po) = *(const uint4*)(gbh + ci * 16);
    *(uint4*)(Bl + po) = *(const uint4*)(gbl + ci * 16);
  }

  int w = tid >> 6, lane = tid & 63;
  int quad = lane >> 4, l15 = lane & 15;
  int nw = n0 + w * 64;

  const char* abase = (const char*)xaggb + (size_t)h * N * 256;
  short8 a[4][4];
#pragma unroll
  for (int mt = 0; mt < 4; ++mt) {
    int node = nw + mt * 16 + l15;
    if (node >= N) node = N - 1;
    const char* rowp = abase + (size_t)node * 256 + quad * 16;
#pragma unroll
    for (int ks = 0; ks < 4; ++ks)
      a[mt][ks] = *(const short8*)(rowp + ks * 64);
  }
  __syncthreads();

  float ucr[8], usr[8], udr[8];
  floatx4 acc[4][8];
#pragma unroll
  for (int jt = 0; jt < 8; ++jt) {
    int jl = jt * 16 + l15;
    float b = sh[jl];
    ucr[jt] = sh[128 + jl];
    usr[jt] = sh[256 + jl];
    udr[jt] = sh[384 + jl];
#pragma unroll
    for (int mt = 0; mt < 4; ++mt) acc[mt][jt] = (floatx4)(b);
  }

  for (int ks = 0; ks < 4; ++ks) {
    int xo = (((ks * 4 + quad) ^ l15) << 4);
#pragma unroll
    for (int jt = 0; jt < 8; ++jt) {
      int po = (jt * 16 + l15) * 256 + xo;
      short8 wh = *(const short8*)(Bh + po);
      short8 wl = *(const short8*)(Bl + po);
#pragma unroll
      for (int mt = 0; mt < 4; ++mt) {
        acc[mt][jt] = __builtin_amdgcn_mfma_f32_16x16x32_bf16(a[mt][ks], wh, acc[mt][jt], 0, 0, 0);
        acc[mt][jt] = __builtin_amdgcn_mfma_f32_16x16x32_bf16(a[mt][ks], wl, acc[mt][jt], 0, 0, 0);
      }
    }
  }

#pragma unroll
  for (int mt = 0; mt < 4; ++mt) {
#pragma unroll
    for (int r = 0; r < 4; ++r) {
      int node = nw + mt * 16 + quad * 4 + r;
      float pc = 0.f, ps = 0.f, pd = 0.f;
#pragma unroll
      for (int jt = 0; jt < 8; ++jt) {
        float v = acc[mt][jt][r];
        float e = v > 0.f ? v : expm1f(v);
        pc += e * ucr[jt];
        ps += e * usr[jt];
        pd += e * udr[jt];
      }
#pragma unroll
      for (int off = 1; off <= 8; off <<= 1) {
        pc += __shfl_xor(pc, off);
        ps += __shfl_xor(ps, off);
        pd += __shfl_xor(pd, off);
      }
      if (l15 == 0 && node < N) {
        atomicAdd(&partc[node], pc);
        atomicAdd(&parts[node], ps);
        atomicAdd(&partd[node], pd);
      }
    }
  }
}

// ---------------- layer-2 attention, all-scalar, single pass (no max) ----------------

__global__ __launch_bounds__(256) void k_attn2s(const float* __restrict__ partc,
                                                const float* __restrict__ parts,
                                                const float* __restrict__ partd,
                                                const int* __restrict__ row_ptr,
                                                const int* __restrict__ csr,
                                                const float* __restrict__ cconst,
                                                float* __restrict__ out, int N) {
  int w = threadIdx.x >> 6, lane = threadIdx.x & 63;
  int d = blockIdx.x * 4 + w;
  if (d >= N) return;
  int e0 = row_ptr[d], deg = row_ptr[d + 1] - e0;
  float aldd = partd[d];
  float z = 0.f, num = 0.f;
  for (int e = lane; e < deg; e += 64) {
    int s = csr[e0 + e];
    float v = __expf(leaky(parts[s] + aldd));
    z += v;
    num += v * partc[s];
  }
#pragma unroll
  for (int off = 32; off; off >>= 1) {
    z += __shfl_xor(z, off);
    num += __shfl_xor(num, off);
  }
  if (lane == 0) out[d] = num / (z + 1e-16f) + cconst[0];
}

// ---------------- launch ----------------

extern "C" void kernel_launch(void* const* d_in, const int* in_sizes, int n_in,
                              void* d_out, int out_size, void* d_ws, size_t ws_size,
                              hipStream_t stream) {
  const float* x      = (const float*)d_in[0];
  const int*   ei     = (const int*)d_in[1];
  const float* W1     = (const float*)d_in[2];
  const float* a_src1 = (const float*)d_in[3];
  const float* a_dst1 = (const float*)d_in[4];
  const float* b1     = (const float*)d_in[5];
  const float* W2     = (const float*)d_in[6];
  const float* a_src2 = (const float*)d_in[7];
  const float* a_dst2 = (const float*)d_in[8];
  const float* b2     = (const float*)d_in[9];
  const float* Wc     = (const float*)d_in[10];
  const float* bc     = (const float*)d_in[11];

  int N = in_sizes[0] / EMBED;
  int E = in_sizes[1] / 2;
  int Et = E + N;
  int nScanB = (N + 255) / 256;

  char* ws = (char*)d_ws;
  size_t off = 0;
  auto alloc = [&](size_t bytes) -> void* {
    void* p = ws + off;
    off += (bytes + 255) & ~(size_t)255;
    return p;
  };
  __hip_bfloat16* xaggb = (__hip_bfloat16*)alloc((size_t)N * 2048 * 2 + 65536);
  short* w1t_hi = (short*)alloc((size_t)262144 * 2);
  short* w1t_lo = (short*)alloc((size_t)262144 * 2);
  float* wsAll  = (float*)alloc(4096 * 4);
  float* uvec   = (float*)alloc(6144 * 4);
  float* cconst = (float*)alloc(256);
  float* als1   = (float*)alloc((size_t)N * 16 * 4);
  float* ald1   = (float*)alloc((size_t)N * 16 * 4);
  float* part   = (float*)alloc((size_t)3 * N * 4);
  float* partc  = part;
  float* parts  = part + N;
  float* partd  = part + 2 * N;
  int* deg      = (int*)alloc((size_t)N * 4);
  int* excl     = (int*)alloc((size_t)N * 4);
  int* bsum     = (int*)alloc((size_t)(nScanB + 1) * 4);
  int* row_ptr  = (int*)alloc((size_t)(N + 1) * 4);
  int* cursor   = (int*)alloc((size_t)N * 4);
  int* csr      = (int*)alloc((size_t)Et * 4);

  hipMemsetAsync(deg, 0, (size_t)N * 4, stream);
  hipMemsetAsync(part, 0, (size_t)3 * N * 4, stream);

  k_hist<<<(Et + 255) / 256, 256, 0, stream>>>(ei, E, N, deg);
  k_scan1<<<nScanB, 256, 0, stream>>>(deg, excl, bsum, N);
  k_scan2<<<1, 64, 0, stream>>>(bsum, nScanB);
  k_scan3<<<nScanB, 256, 0, stream>>>(deg, excl, bsum, row_ptr, cursor, N);
  k_scatter<<<(Et + 255) / 256, 256, 0, stream>>>(ei, E, N, cursor, csr);

  k_prepAll<<<41, 256, 0, stream>>>(W1, a_src1, a_dst1, W2, a_src2, a_dst2, Wc, b2, bc,
                                    wsAll, uvec, cconst);
  k_prep2aT<<<dim3(16, 2, 2), 256, 0, stream>>>(W1, w1t_hi, w1t_lo);

  k_al1v2<<<(N * 16 + 255) / 256, 256, 0, stream>>>(x, wsAll, als1, ald1, N);
  k_attn1d<<<N, 256, 0, stream>>>(x, als1, ald1, row_ptr, csr, xaggb, N);

  k_fused<<<dim3((N + 255) / 256, 16), 256, 0, stream>>>(xaggb, w1t_hi, w1t_lo, b1, uvec,
                                                         partc, parts, partd, N);
  k_attn2s<<<(N + 3) / 4, 256, 0, stream>>>(partc, parts, partd, row_ptr, csr, cconst,
                                            (float*)d_out, N);
}

// Round 10
// 203.738 us; speedup vs baseline: 3.0279x; 1.0614x over previous
//
#include <hip/hip_runtime.h>
#include <hip/hip_bf16.h>

#define EMBED 128
#define HEADS 16
#define NEG 0.2f

typedef __attribute__((ext_vector_type(8))) short short8;
typedef __attribute__((ext_vector_type(4))) float floatx4;

static __device__ __forceinline__ float leaky(float x) { return x > 0.f ? x : NEG * x; }

static __device__ __forceinline__ short f2bf_bits(float f) {
  __hip_bfloat16 h = __float2bfloat16(f);
  union { __hip_bfloat16 b; short s; } u;
  u.b = h;
  return u.s;
}

// ---------------- CSR build ----------------

__global__ void k_hist(const int* __restrict__ ei, int E, int N, int* __restrict__ deg) {
  int i = blockIdx.x * blockDim.x + threadIdx.x;
  int Et = E + N;
  if (i >= Et) return;
  int d = (i < E) ? ei[E + i] : (i - E);
  atomicAdd(&deg[d], 1);
}

__global__ __launch_bounds__(256) void k_scan1(const int* __restrict__ deg,
                                               int* __restrict__ excl,
                                               int* __restrict__ bsum, int n) {
  __shared__ int s[256];
  int i = blockIdx.x * 256 + threadIdx.x;
  int v = (i < n) ? deg[i] : 0;
  s[threadIdx.x] = v;
  __syncthreads();
  for (int d = 1; d < 256; d <<= 1) {
    int add = ((int)threadIdx.x >= d) ? s[threadIdx.x - d] : 0;
    __syncthreads();
    s[threadIdx.x] += add;
    __syncthreads();
  }
  if (i < n) excl[i] = s[threadIdx.x] - v;
  if (threadIdx.x == 255) bsum[blockIdx.x] = s[255];
}

__global__ void k_scan2(int* __restrict__ bsum, int nb) {
  if (threadIdx.x == 0 && blockIdx.x == 0) {
    int acc = 0;
    for (int i = 0; i < nb; ++i) { int v = bsum[i]; bsum[i] = acc; acc += v; }
  }
}

__global__ __launch_bounds__(256) void k_scan3(const int* __restrict__ deg,
                                               const int* __restrict__ excl,
                                               const int* __restrict__ bsum,
                                               int* __restrict__ row_ptr,
                                               int* __restrict__ cursor, int n) {
  int i = blockIdx.x * 256 + threadIdx.x;
  if (i < n) {
    int r = excl[i] + bsum[blockIdx.x];
    row_ptr[i] = r;
    cursor[i] = r;
    if (i == n - 1) row_ptr[n] = r + deg[i];
  }
}

__global__ void k_scatter(const int* __restrict__ ei, int E, int N,
                          int* __restrict__ cursor, int* __restrict__ csr_src) {
  int i = blockIdx.x * blockDim.x + threadIdx.x;
  int Et = E + N;
  if (i >= Et) return;
  int s = (i < E) ? ei[i] : (i - E);
  int d = (i < E) ? ei[E + i] : (i - E);
  int pos = atomicAdd(&cursor[d], 1);
  csr_src[pos] = s;
}

// ---------------- merged prep: w~ vectors (layer1 logits) + u vectors (layer2 folded) ----------------

__global__ __launch_bounds__(256) void k_prepAll(const float* __restrict__ W1,
                                                 const float* __restrict__ a_src1,
                                                 const float* __restrict__ a_dst1,
                                                 const float* __restrict__ W2,
                                                 const float* __restrict__ a_src2,
                                                 const float* __restrict__ a_dst2,
                                                 const float* __restrict__ Wc,
                                                 const float* __restrict__ b2,
                                                 const float* __restrict__ bc,
                                                 float* __restrict__ wsAll,
                                                 float* __restrict__ uvec,
                                                 float* __restrict__ cconst) {
  int gid = blockIdx.x * 256 + threadIdx.x;
  if (gid < 4096) {
    int sel = gid >> 11;
    int id = gid & 2047;
    int h = id >> 7, k = id & 127;
    const float* av = sel ? a_dst1 : a_src1;
    float sum = 0.f;
    const float* wrow = W1 + (size_t)k * 2048 + h * 128;
    const float* arow = av + h * 128;
#pragma unroll 4
    for (int c = 0; c < 128; ++c) sum += wrow[c] * arow[c];
    wsAll[gid] = sum;
  } else if (gid < 10240) {
    int g = gid - 4096;
    int sel = g >> 11;  // 0: Wc, 1: a_src2, 2: a_dst2
    int k = g & 2047;
    const float* v = sel == 0 ? Wc : (sel == 1 ? a_src2 : a_dst2);
    const float* wrow = W2 + (size_t)k * 128;
    float s = 0.f;
#pragma unroll 4
    for (int j = 0; j < 128; ++j) s += wrow[j] * v[j];
    uvec[g] = s;
  } else if (gid == 10240) {
    float s = 0.f;
    for (int j = 0; j < 128; ++j) s += b2[j] * Wc[j];
    *cconst = s + bc[0];
  }
}

// ---------------- W1^T hi/lo bf16 via LDS tile transpose: layout [h][j][c] ----------------

__global__ __launch_bounds__(256) void k_prep2aT(const float* __restrict__ W1,
                                                 short* __restrict__ hi,
                                                 short* __restrict__ lo) {
  __shared__ float tile[64][65];
  int h = blockIdx.x;
  int c0 = blockIdx.y * 64;
  int j0 = blockIdx.z * 64;
  int t = threadIdx.x;
#pragma unroll
  for (int i = 0; i < 4; ++i) {
    int idx4 = i * 256 + t;
    int c = idx4 >> 4, j4 = idx4 & 15;
    float4 v = *(const float4*)&W1[(size_t)(c0 + c) * 2048 + h * 128 + j0 + j4 * 4];
    tile[c][j4 * 4 + 0] = v.x;
    tile[c][j4 * 4 + 1] = v.y;
    tile[c][j4 * 4 + 2] = v.z;
    tile[c][j4 * 4 + 3] = v.w;
  }
  __syncthreads();
#pragma unroll
  for (int i = 0; i < 4; ++i) {
    int idx = i * 256 + t;
    int j = idx >> 4, c4 = idx & 15;
    unsigned short vh[4], vl[4];
#pragma unroll
    for (int ii = 0; ii < 4; ++ii) {
      float wv = tile[c4 * 4 + ii][j];
      short hb = f2bf_bits(wv);
      float hf = __uint_as_float(((unsigned int)(unsigned short)hb) << 16);
      vh[ii] = (unsigned short)hb;
      vl[ii] = (unsigned short)f2bf_bits(wv - hf);
    }
    size_t o = (size_t)h * 16384 + (size_t)(j0 + j) * 128 + c0 + c4 * 4;
    *(ushort4*)&hi[o] = make_ushort4(vh[0], vh[1], vh[2], vh[3]);
    *(ushort4*)&lo[o] = make_ushort4(vl[0], vl[1], vl[2], vl[3]);
  }
}

// ---------------- layer-1 logits: thread per (n,h); weights [c][h] in LDS ----------------

__global__ __launch_bounds__(256) void k_al1v2(const float* __restrict__ x,
                                               const float* __restrict__ wsAll,
                                               float* __restrict__ als,
                                               float* __restrict__ ald, int N) {
  __shared__ float wss[128][16], wsd[128][16];
  int tid = threadIdx.x;
  for (int i = tid; i < 2048; i += 256) {
    int h = i >> 7, c = i & 127;
    wss[c][h] = wsAll[i];
    wsd[c][h] = wsAll[2048 + i];
  }
  __syncthreads();
  int gid = blockIdx.x * 256 + tid;
  int n = gid >> 4, h = gid & 15;
  if (n >= N) return;
  const float4* xp = (const float4*)(x + (size_t)n * 128);
  float ps = 0.f, pd = 0.f;
#pragma unroll 8
  for (int c4 = 0; c4 < 32; ++c4) {
    float4 xv = xp[c4];
    int c = c4 * 4;
    ps += xv.x * wss[c][h] + xv.y * wss[c + 1][h] + xv.z * wss[c + 2][h] + xv.w * wss[c + 3][h];
    pd += xv.x * wsd[c][h] + xv.y * wsd[c + 1][h] + xv.z * wsd[c + 2][h] + xv.w * wsd[c + 3][h];
  }
  als[gid] = ps;
  ald[gid] = pd;
}

// ---------------- layer-1 attention, wave-per-node (no LDS, no syncs) ----------------
// lane = es*16 + h. Pass 1: z via 4-way-strided edge loop + 2 xor shuffles.
// Pass 2: lane owns channels {lane*2, lane*2+1} for ALL 16 heads (32 acc regs);
// per edge: coalesced 512B x-row read + 16 lane-broadcasts + 32 FMA.
// xagg layout: HEAD-MAJOR [16][N][128].

__global__ __launch_bounds__(256) void k_attn1w(const float* __restrict__ x,
                                                const float* __restrict__ als,
                                                const float* __restrict__ ald,
                                                const int* __restrict__ row_ptr,
                                                const int* __restrict__ csr,
                                                __hip_bfloat16* __restrict__ xaggb,
                                                int N) {
  int tid = threadIdx.x;
  int d = blockIdx.x * 4 + (tid >> 6);
  if (d >= N) return;
  int lane = tid & 63;
  int h = lane & 15, es = lane >> 4;
  int grp = lane & 48;

  int e0 = row_ptr[d];
  int deg = row_ptr[d + 1] - e0;

  float aldh = ald[(size_t)d * 16 + h];

  // pass 1: z
  float zp = 0.f;
  for (int e = es; e < deg; e += 4) {
    int s = csr[e0 + e];
    zp += __expf(leaky(als[(size_t)s * 16 + h] + aldh));
  }
  zp += __shfl_xor(zp, 16);
  zp += __shfl_xor(zp, 32);
  float iz = 1.f / (zp + 1e-16f);

  // pass 2: aggregate
  float accx[16], accy[16];
#pragma unroll
  for (int k = 0; k < 16; ++k) { accx[k] = 0.f; accy[k] = 0.f; }

  const float* xc = x + lane * 2;
  for (int e = 0; e < deg; ++e) {
    int s = csr[e0 + e];
    float ev = __expf(leaky(als[(size_t)s * 16 + h] + aldh)) * iz;
    float2 xv = *(const float2*)(xc + (size_t)s * 128);
#pragma unroll
    for (int k = 0; k < 16; ++k) {
      float a = __shfl(ev, grp | k);
      accx[k] += a * xv.x;
      accy[k] += a * xv.y;
    }
  }

  __hip_bfloat16* op = xaggb + (size_t)d * 128 + lane * 2;
#pragma unroll
  for (int k = 0; k < 16; ++k) {
    __hip_bfloat16 t[2];
    t[0] = __float2bfloat16(accx[k]);
    t[1] = __float2bfloat16(accy[k]);
    *(unsigned int*)(op + (size_t)k * N * 128) = *(unsigned int*)t;
  }
}

// ---------------- fused v5: block = (256 nodes, 1 head). B in LDS (swizzled), A in VGPRs. ----------------
// OPERAND-SWAPPED MFMA: D[j-row, node-col] -> u-contraction reduces over reg idx + jt
// (in-lane) and quad (2 shuffles). b1 folded into C-init per-r. ELU via __expf.

__global__ __launch_bounds__(256, 2) void k_fused(const __hip_bfloat16* __restrict__ xaggb,
                                                  const short* __restrict__ w1t_hi,
                                                  const short* __restrict__ w1t_lo,
                                                  const float* __restrict__ b1,
                                                  const float* __restrict__ uvec,
                                                  float* __restrict__ partc,
                                                  float* __restrict__ parts,
                                                  float* __restrict__ partd,
                                                  int N) {
  __shared__ float sh[512];                       // b1 | uc | us | ud (head slice)
  __shared__ __align__(16) char Bh[32768];        // 128 j x 256B (hi), 16B-chunk XOR swizzle
  __shared__ __align__(16) char Bl[32768];        // (lo)
  int tid = threadIdx.x;
  int h = blockIdx.y;
  int n0 = blockIdx.x * 256;

  for (int i = tid; i < 512; i += 256) {
    int arr = i >> 7, jj = i & 127;
    sh[i] = (arr == 0) ? b1[h * 128 + jj] : uvec[(arr - 1) * 2048 + h * 128 + jj];
  }
  const char* gbh = (const char*)(w1t_hi + (size_t)h * 16384);
  const char* gbl = (const char*)(w1t_lo + (size_t)h * 16384);
#pragma unroll
  for (int i = 0; i < 8; ++i) {
    int ci = i * 256 + tid;          // 0..2047
    int row = ci >> 4, kc = ci & 15;
    int po = row * 256 + ((kc ^ (row & 15)) << 4);
    *(uint4*)(Bh + po) = *(const uint4*)(gbh + ci * 16);
    *(uint4*)(Bl + po) = *(const uint4*)(gbl + ci * 16);
  }

  int w = tid >> 6, lane = tid & 63;
  int quad = lane >> 4, l15 = lane & 15;
  int nw = n0 + w * 64;

  // x fragments (MFMA B operand): B[k=quad*8+i][n=l15]
  const char* abase = (const char*)xaggb + (size_t)h * N * 256;
  short8 a[4][4];
#pragma unroll
  for (int nt = 0; nt < 4; ++nt) {
    int node = nw + nt * 16 + l15;
    if (node >= N) node = N - 1;
    const char* rowp = abase + (size_t)node * 256 + quad * 16;
#pragma unroll
    for (int ks = 0; ks < 4; ++ks)
      a[nt][ks] = *(const short8*)(rowp + ks * 64);
  }
  __syncthreads();

  // C-init: acc[nt][jt][r] = b1[jt*16 + quad*4 + r]
  floatx4 acc[4][8];
#pragma unroll
  for (int jt = 0; jt < 8; ++jt) {
    floatx4 bb = *(const floatx4*)&sh[jt * 16 + quad * 4];
#pragma unroll
    for (int nt = 0; nt < 4; ++nt) acc[nt][jt] = bb;
  }

  for (int ks = 0; ks < 4; ++ks) {
    int xo = (((ks * 4 + quad) ^ l15) << 4);
#pragma unroll
    for (int jt = 0; jt < 8; ++jt) {
      int po = (jt * 16 + l15) * 256 + xo;
      short8 wh = *(const short8*)(Bh + po);
      short8 wl = *(const short8*)(Bl + po);
#pragma unroll
      for (int nt = 0; nt < 4; ++nt) {
        acc[nt][jt] = __builtin_amdgcn_mfma_f32_16x16x32_bf16(wh, a[nt][ks], acc[nt][jt], 0, 0, 0);
        acc[nt][jt] = __builtin_amdgcn_mfma_f32_16x16x32_bf16(wl, a[nt][ks], acc[nt][jt], 0, 0, 0);
      }
    }
  }

  // epilogue: ELU + contract with u over j (reg r + jt in-lane, quad via 2 shuffles)
  float pc[4] = {0.f, 0.f, 0.f, 0.f};
  float ps[4] = {0.f, 0.f, 0.f, 0.f};
  float pd[4] = {0.f, 0.f, 0.f, 0.f};
#pragma unroll
  for (int jt = 0; jt < 8; ++jt) {
    floatx4 uc = *(const floatx4*)&sh[128 + jt * 16 + quad * 4];
    floatx4 us = *(const floatx4*)&sh[256 + jt * 16 + quad * 4];
    floatx4 ud = *(const floatx4*)&sh[384 + jt * 16 + quad * 4];
#pragma unroll
    for (int nt = 0; nt < 4; ++nt) {
#pragma unroll
      for (int r = 0; r < 4; ++r) {
        float v = acc[nt][jt][r];
        float e = v > 0.f ? v : (__expf(v) - 1.f);
        pc[nt] += e * uc[r];
        ps[nt] += e * us[r];
        pd[nt] += e * ud[r];
      }
    }
  }
#pragma unroll
  for (int nt = 0; nt < 4; ++nt) {
    float c = pc[nt], s = ps[nt], dd = pd[nt];
    c += __shfl_xor(c, 16); c += __shfl_xor(c, 32);
    s += __shfl_xor(s, 16); s += __shfl_xor(s, 32);
    dd += __shfl_xor(dd, 16); dd += __shfl_xor(dd, 32);
    int node = nw + nt * 16 + l15;
    if (quad == 0 && node < N) {
      atomicAdd(&partc[node], c);
      atomicAdd(&parts[node], s);
      atomicAdd(&partd[node], dd);
    }
  }
}

// ---------------- layer-2 attention, all-scalar, single pass (no max) ----------------

__global__ __launch_bounds__(256) void k_attn2s(const float* __restrict__ partc,
                                                const float* __restrict__ parts,
                                                const float* __restrict__ partd,
                                                const int* __restrict__ row_ptr,
                                                const int* __restrict__ csr,
                                                const float* __restrict__ cconst,
                                                float* __restrict__ out, int N) {
  int w = threadIdx.x >> 6, lane = threadIdx.x & 63;
  int d = blockIdx.x * 4 + w;
  if (d >= N) return;
  int e0 = row_ptr[d], deg = row_ptr[d + 1] - e0;
  float aldd = partd[d];
  float z = 0.f, num = 0.f;
  for (int e = lane; e < deg; e += 64) {
    int s = csr[e0 + e];
    float v = __expf(leaky(parts[s] + aldd));
    z += v;
    num += v * partc[s];
  }
#pragma unroll
  for (int off = 32; off; off >>= 1) {
    z += __shfl_xor(z, off);
    num += __shfl_xor(num, off);
  }
  if (lane == 0) out[d] = num / (z + 1e-16f) + cconst[0];
}

// ---------------- launch ----------------

extern "C" void kernel_launch(void* const* d_in, const int* in_sizes, int n_in,
                              void* d_out, int out_size, void* d_ws, size_t ws_size,
                              hipStream_t stream) {
  const float* x      = (const float*)d_in[0];
  const int*   ei     = (const int*)d_in[1];
  const float* W1     = (const float*)d_in[2];
  const float* a_src1 = (const float*)d_in[3];
  const float* a_dst1 = (const float*)d_in[4];
  const float* b1     = (const float*)d_in[5];
  const float* W2     = (const float*)d_in[6];
  const float* a_src2 = (const float*)d_in[7];
  const float* a_dst2 = (const float*)d_in[8];
  const float* b2     = (const float*)d_in[9];
  const float* Wc     = (const float*)d_in[10];
  const float* bc     = (const float*)d_in[11];

  int N = in_sizes[0] / EMBED;
  int E = in_sizes[1] / 2;
  int Et = E + N;
  int nScanB = (N + 255) / 256;

  char* ws = (char*)d_ws;
  size_t off = 0;
  auto alloc = [&](size_t bytes) -> void* {
    void* p = ws + off;
    off += (bytes + 255) & ~(size_t)255;
    return p;
  };
  __hip_bfloat16* xaggb = (__hip_bfloat16*)alloc((size_t)N * 2048 * 2 + 65536);
  short* w1t_hi = (short*)alloc((size_t)262144 * 2);
  short* w1t_lo = (short*)alloc((size_t)262144 * 2);
  float* wsAll  = (float*)alloc(4096 * 4);
  float* uvec   = (float*)alloc(6144 * 4);
  float* cconst = (float*)alloc(256);
  float* als1   = (float*)alloc((size_t)N * 16 * 4);
  float* ald1   = (float*)alloc((size_t)N * 16 * 4);
  float* part   = (float*)alloc((size_t)3 * N * 4);
  float* partc  = part;
  float* parts  = part + N;
  float* partd  = part + 2 * N;
  int* deg      = (int*)alloc((size_t)N * 4);
  int* excl     = (int*)alloc((size_t)N * 4);
  int* bsum     = (int*)alloc((size_t)(nScanB + 1) * 4);
  int* row_ptr  = (int*)alloc((size_t)(N + 1) * 4);
  int* cursor   = (int*)alloc((size_t)N * 4);
  int* csr      = (int*)alloc((size_t)Et * 4);

  hipMemsetAsync(deg, 0, (size_t)N * 4, stream);
  hipMemsetAsync(part, 0, (size_t)3 * N * 4, stream);

  k_hist<<<(Et + 255) / 256, 256, 0, stream>>>(ei, E, N, deg);
  k_scan1<<<nScanB, 256, 0, stream>>>(deg, excl, bsum, N);
  k_scan2<<<1, 64, 0, stream>>>(bsum, nScanB);
  k_scan3<<<nScanB, 256, 0, stream>>>(deg, excl, bsum, row_ptr, cursor, N);
  k_scatter<<<(Et + 255) / 256, 256, 0, stream>>>(ei, E, N, cursor, csr);

  k_prepAll<<<41, 256, 0, stream>>>(W1, a_src1, a_dst1, W2, a_src2, a_dst2, Wc, b2, bc,
                                    wsAll, uvec, cconst);
  k_prep2aT<<<dim3(16, 2, 2), 256, 0, stream>>>(W1, w1t_hi, w1t_lo);

  k_al1v2<<<(N * 16 + 255) / 256, 256, 0, stream>>>(x, wsAll, als1, ald1, N);
  k_attn1w<<<(N + 3) / 4, 256, 0, stream>>>(x, als1, ald1, row_ptr, csr, xaggb, N);

  k_fused<<<dim3((N + 255) / 256, 16), 256, 0, stream>>>(xaggb, w1t_hi, w1t_lo, b1, uvec,
                                                         partc, parts, partd, N);
  k_attn2s<<<(N + 3) / 4, 256, 0, stream>>>(partc, parts, partd, row_ptr, csr, cconst,
                                            (float*)d_out, N);
}